// Round 9
// baseline (302.820 us; speedup 1.0000x reference)
//
#include <hip/hip_runtime.h>
#include <hip/hip_bf16.h>
#include <math.h>

#define B 64
#define H 1024
#define SEQ 256
#define V 50257
#define NBLK 786   // ceil(V/64)

typedef float4 f4;
typedef __attribute__((ext_vector_type(4))) float f32x4;
typedef __attribute__((ext_vector_type(8))) short bf16x8;

__device__ inline float sigm(float x){ return 1.0f/(1.0f+expf(-x)); }
__device__ inline short f2bf(float x){
  __hip_bfloat16 h = __float2bfloat16(x);
  union { __hip_bfloat16 h; short s; } u; u.h = h; return u.s;
}
__device__ inline short2 cvt2(float x, float y){
  __hip_bfloat162 h = __float22bfloat162_rn(float2{x, y});
  union { __hip_bfloat162 h; short2 s; } u; u.h = h; return u.s;
}
__device__ inline bf16x8 pack8(f4 lo, f4 hi){
  union { bf16x8 v; short2 s[4]; } u;
  u.s[0]=cvt2(lo.x,lo.y); u.s[1]=cvt2(lo.z,lo.w);
  u.s[2]=cvt2(hi.x,hi.y); u.s[3]=cvt2(hi.z,hi.w);
  return u.v;
}
__device__ inline float wrsum(float v){
  #pragma unroll
  for(int o=32;o;o>>=1) v += __shfl_xor(v,o);
  return v;
}
__device__ inline float wrmax(float v){
  #pragma unroll
  for(int o=32;o;o>>=1) v = fmaxf(v,__shfl_xor(v,o));
  return v;
}
__device__ inline f32x4 mfma16(bf16x8 a, bf16x8 b, f32x4 c){
  return __builtin_amdgcn_mfma_f32_16x16x32_bf16(a,b,c,0,0,0);
}

// ---- 1: build X_b[:, :3072] = bf16[emb(iw) | lasth | ictx] ----
__global__ void k_build(const int* __restrict__ istep,
                        const float* __restrict__ lasth, const float* __restrict__ ictx,
                        const float* __restrict__ emb, short* __restrict__ X_b){
  int b = blockIdx.x; int h = threadIdx.x*4;
  int iw = istep[b];
  f4 lw = *(const f4*)(emb  + (size_t)iw*H + h);
  f4 hs = *(const f4*)(lasth + (size_t)b*H + h);
  f4 cv = *(const f4*)(ictx + (size_t)b*H + h);
  short* xb = X_b + (size_t)b*4096;
  *(short4*)(xb +        h) = make_short4(f2bf(lw.x),f2bf(lw.y),f2bf(lw.z),f2bf(lw.w));
  *(short4*)(xb + 1024 + h) = make_short4(f2bf(hs.x),f2bf(hs.y),f2bf(hs.z),f2bf(hs.w));
  *(short4*)(xb + 2048 + h) = make_short4(f2bf(cv.x),f2bf(cv.y),f2bf(cv.z),f2bf(cv.w));
}

// ---- 2: blocks 0..63: W_read gemm + sigmoid*eemb -> emog f32 + X_b[:,3072:] bf16
//         blocks 64..255: W_hh gemm (192 tiles) -> gh raw f32 ----
__launch_bounds__(256)
__global__ void k_pre(const int* __restrict__ iemo, const short* __restrict__ X_b,
                      const float* __restrict__ eemb,
                      const float* __restrict__ Wread, const float* __restrict__ bread,
                      const float* __restrict__ Whh,
                      float* __restrict__ emog, short* __restrict__ X_b_w,
                      float* __restrict__ gh){
  __shared__ float red[4][64][20];
  int tid = threadIdx.x;
  int w = tid>>6, l = tid&63, lm = l&15, lq = l>>4;
  f32x4 acc0={0,0,0,0}, acc1={0,0,0,0}, acc2={0,0,0,0}, acc3={0,0,0,0};
  int readmode = (blockIdx.x < 64);
  int tile = readmode ? blockIdx.x : (blockIdx.x - 64);
  int ncol = tile*16 + lm;
  const float* wp = readmode ? (Wread + (size_t)ncol*3072 + lq*8)
                             : (Whh   + (size_t)ncol*1024 + lq*8);
  const short* ap = readmode ? (X_b + lm*4096 + lq*8)
                             : (X_b + 1024 + lm*4096 + lq*8);
  int kbeg = readmode ? w*768 : w*256;
  int kend = readmode ? (kbeg + 768) : (kbeg + 256);
  for(int k0=kbeg; k0<kend; k0+=64){
    f4 w0 = *(const f4*)(wp + k0);
    f4 w1 = *(const f4*)(wp + k0 + 4);
    f4 w2 = *(const f4*)(wp + k0 + 32);
    f4 w3 = *(const f4*)(wp + k0 + 36);
    bf16x8 a00 = *(const bf16x8*)(ap + k0);
    bf16x8 a01 = *(const bf16x8*)(ap + k0 + 32);
    bf16x8 a10 = *(const bf16x8*)(ap + 16*4096 + k0);
    bf16x8 a11 = *(const bf16x8*)(ap + 16*4096 + k0 + 32);
    bf16x8 a20 = *(const bf16x8*)(ap + 32*4096 + k0);
    bf16x8 a21 = *(const bf16x8*)(ap + 32*4096 + k0 + 32);
    bf16x8 a30 = *(const bf16x8*)(ap + 48*4096 + k0);
    bf16x8 a31 = *(const bf16x8*)(ap + 48*4096 + k0 + 32);
    bf16x8 b0 = pack8(w0,w1), b1 = pack8(w2,w3);
    acc0 = mfma16(a00,b0,acc0); acc1 = mfma16(a10,b0,acc1);
    acc2 = mfma16(a20,b0,acc2); acc3 = mfma16(a30,b0,acc3);
    acc0 = mfma16(a01,b1,acc0); acc1 = mfma16(a11,b1,acc1);
    acc2 = mfma16(a21,b1,acc2); acc3 = mfma16(a31,b1,acc3);
  }
  #pragma unroll
  for(int r=0;r<4;r++){
    red[w][     lq*4+r][lm] = acc0[r];
    red[w][16 + lq*4+r][lm] = acc1[r];
    red[w][32 + lq*4+r][lm] = acc2[r];
    red[w][48 + lq*4+r][lm] = acc3[r];
  }
  __syncthreads();
  int m = tid>>2;
  if(readmode){
    int ie = iemo[m];
    #pragma unroll
    for(int j=0;j<4;j++){
      int c = (tid&3)*4 + j;
      float v = red[0][m][c]+red[1][m][c]+red[2][m][c]+red[3][m][c];
      int n = tile*16 + c;
      float s = sigm(v + bread[n]);
      float eg = s * eemb[(size_t)ie*1024 + n];
      emog[(size_t)m*1024 + n] = eg;
      X_b_w[(size_t)m*4096 + 3072 + n] = f2bf(eg);
    }
  } else {
    #pragma unroll
    for(int j=0;j<4;j++){
      int c = (tid&3)*4 + j;
      float v = red[0][m][c]+red[1][m][c]+red[2][m][c]+red[3][m][c];
      gh[(size_t)m*3072 + tile*16 + c] = v;
    }
  }
}

// ---- 3: gi partials = X @ W_ih^T, 2-way K-split (grid (192,2)) ----
__launch_bounds__(256)
__global__ void k_gi(const short* __restrict__ X_b, const float* __restrict__ Wih,
                     float* __restrict__ gp){
  __shared__ float red[4][64][20];
  int tid = threadIdx.x;
  int w = tid>>6, l = tid&63, lm = l&15, lq = l>>4;
  int half = blockIdx.y;
  int ncol = blockIdx.x*16 + lm;
  const float* wp = Wih + (size_t)ncol*4096 + lq*8;
  const short* ap = X_b + lm*4096 + lq*8;
  int kbeg = half*2048 + w*512, kend = kbeg + 512;
  f32x4 acc0={0,0,0,0}, acc1={0,0,0,0}, acc2={0,0,0,0}, acc3={0,0,0,0};
  for(int k0=kbeg; k0<kend; k0+=64){
    f4 w0 = *(const f4*)(wp + k0);
    f4 w1 = *(const f4*)(wp + k0 + 4);
    f4 w2 = *(const f4*)(wp + k0 + 32);
    f4 w3 = *(const f4*)(wp + k0 + 36);
    bf16x8 a00 = *(const bf16x8*)(ap + k0);
    bf16x8 a01 = *(const bf16x8*)(ap + k0 + 32);
    bf16x8 a10 = *(const bf16x8*)(ap + 16*4096 + k0);
    bf16x8 a11 = *(const bf16x8*)(ap + 16*4096 + k0 + 32);
    bf16x8 a20 = *(const bf16x8*)(ap + 32*4096 + k0);
    bf16x8 a21 = *(const bf16x8*)(ap + 32*4096 + k0 + 32);
    bf16x8 a30 = *(const bf16x8*)(ap + 48*4096 + k0);
    bf16x8 a31 = *(const bf16x8*)(ap + 48*4096 + k0 + 32);
    bf16x8 b0 = pack8(w0,w1), b1 = pack8(w2,w3);
    acc0 = mfma16(a00,b0,acc0); acc1 = mfma16(a10,b0,acc1);
    acc2 = mfma16(a20,b0,acc2); acc3 = mfma16(a30,b0,acc3);
    acc0 = mfma16(a01,b1,acc0); acc1 = mfma16(a11,b1,acc1);
    acc2 = mfma16(a21,b1,acc2); acc3 = mfma16(a31,b1,acc3);
  }
  #pragma unroll
  for(int r=0;r<4;r++){
    red[w][     lq*4+r][lm] = acc0[r];
    red[w][16 + lq*4+r][lm] = acc1[r];
    red[w][32 + lq*4+r][lm] = acc2[r];
    red[w][48 + lq*4+r][lm] = acc3[r];
  }
  __syncthreads();
  int m = tid>>2;
  #pragma unroll
  for(int j=0;j<4;j++){
    int c = (tid&3)*4 + j;
    float v = red[0][m][c]+red[1][m][c]+red[2][m][c]+red[3][m][c];
    gp[(size_t)(half*64+m)*3072 + blockIdx.x*16 + c] = v;
  }
}

// ---- 4: GRU elementwise (sums 2 gi partials + biases) ----
__global__ void k_gru(const float* __restrict__ gp, const float* __restrict__ gh,
                      const float* __restrict__ bih, const float* __restrict__ bhh,
                      const float* __restrict__ h0, float* __restrict__ hid,
                      short* __restrict__ hid_b, short* __restrict__ a2_b){
  int t = blockIdx.x*256 + threadIdx.x;   // 16384
  int b = t>>8, j = (t&255)*4;
  const float* gi0 = gp + (size_t)b*3072 + j;
  const float* gi1 = gp + (size_t)(64+b)*3072 + j;
  const float* ghb = gh + (size_t)b*3072 + j;
  f4 h0v = *(const f4*)(h0 + (size_t)b*1024 + j);
  f4 hres; short4 hb;
  #pragma unroll
  for(int c=0;c<4;c++){
    float r = sigm(gi0[c]      + gi1[c]      + bih[j+c]      + ghb[c]      + bhh[j+c]);
    float z = sigm(gi0[1024+c] + gi1[1024+c] + bih[1024+j+c] + ghb[1024+c] + bhh[1024+j+c]);
    float n = tanhf(gi0[2048+c] + gi1[2048+c] + bih[2048+j+c] + r*(ghb[2048+c] + bhh[2048+j+c]));
    float hv = ((const float*)&h0v)[c];
    float h = (1.0f - z)*n + z*hv;
    ((float*)&hres)[c] = h;
    ((short*)&hb)[c] = f2bf(h);
  }
  *(f4*)(hid + (size_t)b*1024 + j) = hres;
  *(short4*)(hid_b + (size_t)b*1024 + j) = hb;
  *(short4*)(a2_b + (size_t)b*2048 + j) = hb;
}

// ---- 5: blocks 0..511: flash attention chunks; blocks 512..575: W_write gemm ----
__launch_bounds__(256)
__global__ void k_flash(const float* __restrict__ enc, const float* __restrict__ hid,
                        float* __restrict__ part, float* __restrict__ ml,
                        const short* __restrict__ hid_b,
                        const float* __restrict__ Wwrite, const float* __restrict__ bwrite,
                        const float* __restrict__ emog, float* __restrict__ memo){
  __shared__ float red[4][64][20];
  int tid = threadIdx.x;
  int w = tid>>6, l = tid&63;
  if(blockIdx.x < 512){
    int b = blockIdx.x>>3, c = blockIdx.x&7;
    int chunk = c*4 + w;
    const float* hp = hid + (size_t)b*1024 + l*16;
    f4 q0 = *(const f4*)(hp), q1 = *(const f4*)(hp+4);
    f4 q2 = *(const f4*)(hp+8), q3 = *(const f4*)(hp+12);
    f4 cx0={0,0,0,0}, cx1={0,0,0,0}, cx2={0,0,0,0}, cx3={0,0,0,0};
    float mx = -1e30f, ls = 0.0f;
    int s0 = c*32 + w*8;
    for(int si=0; si<8; si++){
      const float* ep = enc + ((size_t)(s0+si)*64 + b)*1024 + l*16;
      f4 e0 = *(const f4*)(ep),   e1 = *(const f4*)(ep+4);
      f4 e2 = *(const f4*)(ep+8), e3 = *(const f4*)(ep+12);
      float d = e0.x*q0.x + e0.y*q0.y + e0.z*q0.z + e0.w*q0.w
              + e1.x*q1.x + e1.y*q1.y + e1.z*q1.z + e1.w*q1.w
              + e2.x*q2.x + e2.y*q2.y + e2.z*q2.z + e2.w*q2.w
              + e3.x*q3.x + e3.y*q3.y + e3.z*q3.z + e3.w*q3.w;
      d = wrsum(d);
      float mn = fmaxf(mx, d);
      float a = expf(mx - mn), p = expf(d - mn);
      ls = ls*a + p;
      cx0.x = cx0.x*a + p*e0.x; cx0.y = cx0.y*a + p*e0.y;
      cx0.z = cx0.z*a + p*e0.z; cx0.w = cx0.w*a + p*e0.w;
      cx1.x = cx1.x*a + p*e1.x; cx1.y = cx1.y*a + p*e1.y;
      cx1.z = cx1.z*a + p*e1.z; cx1.w = cx1.w*a + p*e1.w;
      cx2.x = cx2.x*a + p*e2.x; cx2.y = cx2.y*a + p*e2.y;
      cx2.z = cx2.z*a + p*e2.z; cx2.w = cx2.w*a + p*e2.w;
      cx3.x = cx3.x*a + p*e3.x; cx3.y = cx3.y*a + p*e3.y;
      cx3.z = cx3.z*a + p*e3.z; cx3.w = cx3.w*a + p*e3.w;
      mx = mn;
    }
    float* pp = part + ((size_t)b*32 + chunk)*1024 + l*16;
    *(f4*)(pp)    = cx0; *(f4*)(pp+4)  = cx1;
    *(f4*)(pp+8)  = cx2; *(f4*)(pp+12) = cx3;
    if(l==0){ ml[((size_t)b*32+chunk)*2] = mx; ml[((size_t)b*32+chunk)*2+1] = ls; }
  } else {
    int tile = blockIdx.x - 512;
    int lm = l&15, lq = l>>4;
    int ncol = tile*16 + lm;
    const float* wp = Wwrite + (size_t)ncol*1024 + lq*8;
    const short* ap = hid_b + lm*1024 + lq*8;
    int kbeg = w*256, kend = kbeg + 256;
    f32x4 acc0={0,0,0,0}, acc1={0,0,0,0}, acc2={0,0,0,0}, acc3={0,0,0,0};
    for(int k0=kbeg; k0<kend; k0+=64){
      f4 w0 = *(const f4*)(wp + k0);
      f4 w1 = *(const f4*)(wp + k0 + 4);
      f4 w2 = *(const f4*)(wp + k0 + 32);
      f4 w3 = *(const f4*)(wp + k0 + 36);
      bf16x8 a00 = *(const bf16x8*)(ap + k0);
      bf16x8 a01 = *(const bf16x8*)(ap + k0 + 32);
      bf16x8 a10 = *(const bf16x8*)(ap + 16*1024 + k0);
      bf16x8 a11 = *(const bf16x8*)(ap + 16*1024 + k0 + 32);
      bf16x8 a20 = *(const bf16x8*)(ap + 32*1024 + k0);
      bf16x8 a21 = *(const bf16x8*)(ap + 32*1024 + k0 + 32);
      bf16x8 a30 = *(const bf16x8*)(ap + 48*1024 + k0);
      bf16x8 a31 = *(const bf16x8*)(ap + 48*1024 + k0 + 32);
      bf16x8 b0 = pack8(w0,w1), b1 = pack8(w2,w3);
      acc0 = mfma16(a00,b0,acc0); acc1 = mfma16(a10,b0,acc1);
      acc2 = mfma16(a20,b0,acc2); acc3 = mfma16(a30,b0,acc3);
      acc0 = mfma16(a01,b1,acc0); acc1 = mfma16(a11,b1,acc1);
      acc2 = mfma16(a21,b1,acc2); acc3 = mfma16(a31,b1,acc3);
    }
    #pragma unroll
    for(int r=0;r<4;r++){
      red[w][     lq*4+r][lm] = acc0[r];
      red[w][16 + lq*4+r][lm] = acc1[r];
      red[w][32 + lq*4+r][lm] = acc2[r];
      red[w][48 + lq*4+r][lm] = acc3[r];
    }
    __syncthreads();
    int m = tid>>2;
    #pragma unroll
    for(int j=0;j<4;j++){
      int c = (tid&3)*4 + j;
      float v = red[0][m][c]+red[1][m][c]+red[2][m][c]+red[3][m][c];
      int n = tile*16 + c;
      memo[(size_t)m*1024 + n] = sigm(v + bwrite[n]) * emog[(size_t)m*1024 + n];
    }
  }
}

// ---- 6: merge 32 chunk partials -> context f32 (output) + a2_b[:, 1024:] bf16 ----
__global__ void k_ctxr(const float* __restrict__ part, const float* __restrict__ ml,
                       float* __restrict__ ctxo, short* __restrict__ a2_b){
  int b = blockIdx.x; int t = threadIdx.x;
  __shared__ float sscale[32];
  if(t < 64){
    float mc = (t<32) ? ml[((size_t)b*32+t)*2]   : -1e30f;
    float lc = (t<32) ? ml[((size_t)b*32+t)*2+1] : 0.0f;
    float M = wrmax(mc);
    float L = wrsum(lc * expf(mc - M));
    if(t<32) sscale[t] = expf(mc - M) / L;
  }
  __syncthreads();
  int h = t*4;
  f4 acc = {0,0,0,0};
  for(int c=0;c<32;c++){
    f4 p = *(const f4*)(part + ((size_t)b*32 + c)*1024 + h);
    float s = sscale[c];
    acc.x += s*p.x; acc.y += s*p.y; acc.z += s*p.z; acc.w += s*p.w;
  }
  *(f4*)(ctxo + (size_t)b*1024 + h) = acc;
  *(short4*)(a2_b + (size_t)b*2048 + 1024 + h) =
      make_short4(f2bf(acc.x),f2bf(acc.y),f2bf(acc.z),f2bf(acc.w));
}

// ---- 7: concat_out = tanh(a2 @ W_concat^T + b) -> cc_b bf16 ----
__launch_bounds__(256)
__global__ void k_cc(const short* __restrict__ a2_b, const float* __restrict__ Wc,
                     const float* __restrict__ bc, short* __restrict__ cc_b){
  __shared__ float red[4][64][20];
  int tid = threadIdx.x;
  int w = tid>>6, l = tid&63, lm = l&15, lq = l>>4;
  int ncol = blockIdx.x*16 + lm;
  const float* wp = Wc + (size_t)ncol*2048 + lq*8;
  const short* ap = a2_b + lm*2048 + lq*8;
  int kbeg = w*512, kend = kbeg + 512;
  f32x4 acc0={0,0,0,0}, acc1={0,0,0,0}, acc2={0,0,0,0}, acc3={0,0,0,0};
  for(int k0=kbeg; k0<kend; k0+=64){
    f4 w0 = *(const f4*)(wp + k0);
    f4 w1 = *(const f4*)(wp + k0 + 4);
    f4 w2 = *(const f4*)(wp + k0 + 32);
    f4 w3 = *(const f4*)(wp + k0 + 36);
    bf16x8 a00 = *(const bf16x8*)(ap + k0);
    bf16x8 a01 = *(const bf16x8*)(ap + k0 + 32);
    bf16x8 a10 = *(const bf16x8*)(ap + 16*2048 + k0);
    bf16x8 a11 = *(const bf16x8*)(ap + 16*2048 + k0 + 32);
    bf16x8 a20 = *(const bf16x8*)(ap + 32*2048 + k0);
    bf16x8 a21 = *(const bf16x8*)(ap + 32*2048 + k0 + 32);
    bf16x8 a30 = *(const bf16x8*)(ap + 48*2048 + k0);
    bf16x8 a31 = *(const bf16x8*)(ap + 48*2048 + k0 + 32);
    bf16x8 b0 = pack8(w0,w1), b1 = pack8(w2,w3);
    acc0 = mfma16(a00,b0,acc0); acc1 = mfma16(a10,b0,acc1);
    acc2 = mfma16(a20,b0,acc2); acc3 = mfma16(a30,b0,acc3);
    acc0 = mfma16(a01,b1,acc0); acc1 = mfma16(a11,b1,acc1);
    acc2 = mfma16(a21,b1,acc2); acc3 = mfma16(a31,b1,acc3);
  }
  #pragma unroll
  for(int r=0;r<4;r++){
    red[w][     lq*4+r][lm] = acc0[r];
    red[w][16 + lq*4+r][lm] = acc1[r];
    red[w][32 + lq*4+r][lm] = acc2[r];
    red[w][48 + lq*4+r][lm] = acc3[r];
  }
  __syncthreads();
  int m = tid>>2;
  #pragma unroll
  for(int j=0;j<4;j++){
    int c = (tid&3)*4 + j;
    float v = red[0][m][c]+red[1][m][c]+red[2][m][c]+red[3][m][c];
    int n = blockIdx.x*16 + c;
    cc_b[(size_t)m*1024 + n] = f2bf(tanhf(v + bc[n]));
  }
}

// ---- 8: logits = cc @ W_out^T + b_out. A in REGISTERS (wave owns 16 rows),
//         pure W-stream K-loop (no LDS, no barriers), fused row stats ----
__launch_bounds__(256)
__global__ void k_out(const short* __restrict__ A, const float* __restrict__ Wm,
                      const float* __restrict__ bias, const float* __restrict__ wal,
                      const int* __restrict__ mem,
                      float* __restrict__ outf, float* __restrict__ pstat){
  int tid = threadIdx.x;
  int w = tid>>6, l = tid&63;
  int lm = l&15, lq = l>>4;
  int n0 = blockIdx.x*64;

  // preload this wave's A slice: rows w*16..w*16+15, full K, in MFMA frag layout
  bf16x8 aR[32];
  {
    const short* ap = A + (w*16 + lm)*1024 + lq*8;
    #pragma unroll
    for(int ks=0; ks<32; ks++) aR[ks] = *(const bf16x8*)(ap + ks*32);
  }

  // running per-row stats (4 rows per lane-group), all lanes
  float rdd[4]={0,0,0,0};
  float rme[4]={-1e30f,-1e30f,-1e30f,-1e30f}, rse[4]={0,0,0,0};
  float rmg[4]={-1e30f,-1e30f,-1e30f,-1e30f}, rsg[4]={0,0,0,0};

  for(int cg=0; cg<4; cg++){
    int ncol = n0 + cg*16 + lm;
    int nrow = ncol < V ? ncol : V-1;
    const float* wp = Wm + (size_t)nrow*1024 + lq*8;
    f32x4 acc = {0,0,0,0};
    #pragma unroll
    for(int ks=0; ks<32; ks++){
      f4 lo = *(const f4*)(wp + ks*32);
      f4 hi = *(const f4*)(wp + ks*32 + 4);
      acc = mfma16(aR[ks], pack8(lo,hi), acc);
    }
    float bv=0.0f, wv=0.0f; int mv=-1;
    if(ncol < V){ bv = bias[ncol]; wv = wal[ncol]; mv = mem[ncol]; }
    #pragma unroll
    for(int r=0;r<4;r++){
      float v = acc[r] + bv;
      int row = w*16 + lq*4 + r;
      if(ncol < V) outf[(size_t)row*V + ncol] = v;
      // group (16 lanes, same lq): dot-sum, max-first then single-exp sums
      float dd = v*wv;
      float em = (mv==1) ? v : -1e30f;
      float gm = (mv==0) ? v : -1e30f;
      #pragma unroll
      for(int o=1;o<16;o<<=1){
        dd += __shfl_xor(dd,o);
        em = fmaxf(em, __shfl_xor(em,o));
        gm = fmaxf(gm, __shfl_xor(gm,o));
      }
      float pe = (mv==1) ? expf(v - em) : 0.0f;
      float pg = (mv==0) ? expf(v - gm) : 0.0f;
      #pragma unroll
      for(int o=1;o<16;o<<=1){
        pe += __shfl_xor(pe,o);
        pg += __shfl_xor(pg,o);
      }
      // merge into running per-row state
      rdd[r] += dd;
      float nm = fmaxf(rme[r], em);
      rse[r] = rse[r]*expf(rme[r]-nm) + pe*expf(em-nm); rme[r] = nm;
      nm = fmaxf(rmg[r], gm);
      rsg[r] = rsg[r]*expf(rmg[r]-nm) + pg*expf(gm-nm); rmg[r] = nm;
    }
  }
  // each wave owns its 16 rows: lane lm==0 of each lq-group writes 4 rows
  if(lm==0){
    #pragma unroll
    for(int r=0;r<4;r++){
      int row = w*16 + lq*4 + r;
      float* pp = pstat + ((size_t)row*NBLK + blockIdx.x)*6;
      pp[0]=rdd[r]; pp[1]=rme[r]; pp[2]=rse[r]; pp[3]=rmg[r]; pp[4]=rsg[r];
    }
  }
}

// ---- 9: merge per-block stats partials -> stats[b][8] ----
__global__ void k_merge(const float* __restrict__ pstat, float* __restrict__ stats){
  int b = blockIdx.x, t = threadIdx.x;
  float dd=0.0f, me=-1e30f, se=0.0f, mg=-1e30f, sg=0.0f;
  for(int i=t; i<NBLK; i+=256){
    const float* pp = pstat + ((size_t)b*NBLK + i)*6;
    dd += pp[0];
    float m2=pp[1], s2=pp[2];
    float nm=fmaxf(me,m2); se = se*expf(me-nm) + s2*expf(m2-nm); me = nm;
    m2=pp[3]; s2=pp[4];
    nm=fmaxf(mg,m2); sg = sg*expf(mg-nm) + s2*expf(m2-nm); mg = nm;
  }
  #pragma unroll
  for(int o=32;o;o>>=1){
    dd += __shfl_xor(dd,o);
    float m2=__shfl_xor(me,o), s2=__shfl_xor(se,o);
    float nm=fmaxf(me,m2); se = se*expf(me-nm) + s2*expf(m2-nm); me = nm;
    m2=__shfl_xor(mg,o); s2=__shfl_xor(sg,o);
    nm=fmaxf(mg,m2); sg = sg*expf(mg-nm) + s2*expf(m2-nm); mg = nm;
  }
  __shared__ float sm[4][5];
  int wv = t>>6;
  if((t&63)==0){ sm[wv][0]=dd; sm[wv][1]=me; sm[wv][2]=se; sm[wv][3]=mg; sm[wv][4]=sg; }
  __syncthreads();
  if(t==0){
    float D=0, M=-1e30f, S=0, M2=-1e30f, S2=0;
    for(int i=0;i<4;i++){
      D += sm[i][0];
      float m = fmaxf(M, sm[i][1]); S  = S*expf(M-m)  + sm[i][2]*expf(sm[i][1]-m);  M = m;
      float n = fmaxf(M2,sm[i][3]); S2 = S2*expf(M2-n)+ sm[i][4]*expf(sm[i][3]-n); M2 = n;
    }
    stats[b*8+0]=D; stats[b*8+1]=M; stats[b*8+2]=M2; stats[b*8+3]=S; stats[b*8+4]=S2;
  }
}

// ---- 10: dual gated softmax in-place ----
__global__ void k_final(float* __restrict__ logits, const int* __restrict__ mem,
                        const float* __restrict__ stats, const float* __restrict__ balpha){
  int v = blockIdx.x*256 + threadIdx.x;
  int b = blockIdx.y;
  if(v >= V) return;
  float dot = stats[b*8+0], me = stats[b*8+1], mg = stats[b*8+2];
  float se = stats[b*8+3],  sg = stats[b*8+4];
  float g = sigm(dot + balpha[0]);
  float l = logits[(size_t)b*V + v];
  float o = (mem[v]==1) ? (expf(l-me)/se * g) : (expf(l-mg)/sg * (1.0f-g));
  logits[(size_t)b*V + v] = o;
}

extern "C" void kernel_launch(void* const* d_in, const int* in_sizes, int n_in,
                              void* d_out, int out_size, void* d_ws, size_t ws_size,
                              hipStream_t stream){
  const int*   istep   = (const int*)d_in[0];
  const int*   iemo    = (const int*)d_in[1];
  const float* lasth   = (const float*)d_in[2];
  const float* ictx    = (const float*)d_in[3];
  const float* enc     = (const float*)d_in[4];
  const int*   emem    = (const int*)d_in[5];
  const float* emb     = (const float*)d_in[6];
  const float* eemb    = (const float*)d_in[7];
  const float* W_read  = (const float*)d_in[8];
  const float* b_read  = (const float*)d_in[9];
  const float* W_write = (const float*)d_in[10];
  const float* b_write = (const float*)d_in[11];
  const float* W_ih    = (const float*)d_in[12];
  const float* W_hh    = (const float*)d_in[13];
  const float* b_ih    = (const float*)d_in[14];
  const float* b_hh    = (const float*)d_in[15];
  const float* W_concat= (const float*)d_in[16];
  const float* b_concat= (const float*)d_in[17];
  const float* W_out   = (const float*)d_in[18];
  const float* b_out   = (const float*)d_in[19];
  const float* W_alpha = (const float*)d_in[20];
  const float* b_alpha = (const float*)d_in[21];

  short* X_b  = (short*)d_ws;                           // 64x4096 bf16
  float* emog = (float*)((char*)d_ws + 524288);         // 64x1024
  float* gp   = emog + 65536;                           // 2x64x3072 (gi partials)
  float* gh   = gp + 393216;                            // 64x3072
  float* part = gh + 196608;                            // 64x32x1024
  float* ml   = part + 2097152;                         // 64x32x2
  float* stats= ml + 4096;                              // 512
  float* pstat= stats + 512;                            // 64x786x6
  short* hid_b= (short*)(pstat + 64*NBLK*6);            // 64x1024 bf16
  short* a2_b = hid_b + 65536;                          // 64x2048 bf16
  short* cc_b = a2_b + 131072;                          // 64x1024 bf16

  float* out0 = (float*)d_out;          // [64][V]
  float* hid  = out0 + (size_t)B*V;     // [64][1024] (output: hidden)
  float* memo = hid + 65536;            // [64][1024] (output: new_M_emo)
  float* ctxo = memo + 65536;           // [64][1024] (output: context)

  k_build<<<64,256,0,stream>>>(istep, lasth, ictx, emb, X_b);
  k_pre  <<<256,256,0,stream>>>(iemo, X_b, eemb, W_read, b_read, W_hh, emog, X_b, gh);
  k_gi   <<<dim3(192,2),256,0,stream>>>(X_b, W_ih, gp);
  k_gru  <<<64,256,0,stream>>>(gp, gh, b_ih, b_hh, lasth, hid, hid_b, a2_b);
  k_flash<<<576,256,0,stream>>>(enc, hid, part, ml, hid_b, W_write, b_write, emog, memo);
  k_ctxr <<<64,256,0,stream>>>(part, ml, ctxo, a2_b);
  k_cc   <<<64,256,0,stream>>>(a2_b, W_concat, b_concat, cc_b);
  k_out  <<<NBLK,256,0,stream>>>(cc_b, W_out, b_out, W_alpha, emem, out0, pstat);
  k_merge<<<64,256,0,stream>>>(pstat, stats);
  k_final<<<dim3(197,64),256,0,stream>>>(out0, emem, stats, b_alpha);
}

// Round 10
// 261.718 us; speedup vs baseline: 1.1570x; 1.1570x over previous
//
#include <hip/hip_runtime.h>
#include <hip/hip_bf16.h>
#include <math.h>

#define B 64
#define H 1024
#define SEQ 256
#define V 50257
#define NBLK 786   // ceil(V/64)

typedef float4 f4;
typedef __attribute__((ext_vector_type(4))) float f32x4;
typedef __attribute__((ext_vector_type(8))) short bf16x8;

__device__ inline float sigm(float x){ return 1.0f/(1.0f+expf(-x)); }
__device__ inline short f2bf(float x){
  __hip_bfloat16 h = __float2bfloat16(x);
  union { __hip_bfloat16 h; short s; } u; u.h = h; return u.s;
}
__device__ inline short2 cvt2(float x, float y){
  __hip_bfloat162 h = __float22bfloat162_rn(float2{x, y});
  union { __hip_bfloat162 h; short2 s; } u; u.h = h; return u.s;
}
__device__ inline bf16x8 pack8(f4 lo, f4 hi){
  union { bf16x8 v; short2 s[4]; } u;
  u.s[0]=cvt2(lo.x,lo.y); u.s[1]=cvt2(lo.z,lo.w);
  u.s[2]=cvt2(hi.x,hi.y); u.s[3]=cvt2(hi.z,hi.w);
  return u.v;
}
__device__ inline float wrsum(float v){
  #pragma unroll
  for(int o=32;o;o>>=1) v += __shfl_xor(v,o);
  return v;
}
__device__ inline float wrmax(float v){
  #pragma unroll
  for(int o=32;o;o>>=1) v = fmaxf(v,__shfl_xor(v,o));
  return v;
}
__device__ inline f32x4 mfma16(bf16x8 a, bf16x8 b, f32x4 c){
  return __builtin_amdgcn_mfma_f32_16x16x32_bf16(a,b,c,0,0,0);
}

// ---- 1: build X_b[:, :3072] = bf16[emb(iw) | lasth | ictx] ----
__global__ void k_build(const int* __restrict__ istep,
                        const float* __restrict__ lasth, const float* __restrict__ ictx,
                        const float* __restrict__ emb, short* __restrict__ X_b){
  int b = blockIdx.x; int h = threadIdx.x*4;
  int iw = istep[b];
  f4 lw = *(const f4*)(emb  + (size_t)iw*H + h);
  f4 hs = *(const f4*)(lasth + (size_t)b*H + h);
  f4 cv = *(const f4*)(ictx + (size_t)b*H + h);
  short* xb = X_b + (size_t)b*4096;
  *(short4*)(xb +        h) = make_short4(f2bf(lw.x),f2bf(lw.y),f2bf(lw.z),f2bf(lw.w));
  *(short4*)(xb + 1024 + h) = make_short4(f2bf(hs.x),f2bf(hs.y),f2bf(hs.z),f2bf(hs.w));
  *(short4*)(xb + 2048 + h) = make_short4(f2bf(cv.x),f2bf(cv.y),f2bf(cv.z),f2bf(cv.w));
}

// ---- 2: blocks 0..63: W_read gemm + sigmoid*eemb -> emog f32 + X_b[:,3072:] bf16
//         blocks 64..255: W_hh gemm (192 tiles) -> gh raw f32 ----
__launch_bounds__(256)
__global__ void k_pre(const int* __restrict__ iemo, const short* __restrict__ X_b,
                      const float* __restrict__ eemb,
                      const float* __restrict__ Wread, const float* __restrict__ bread,
                      const float* __restrict__ Whh,
                      float* __restrict__ emog, short* __restrict__ X_b_w,
                      float* __restrict__ gh){
  __shared__ float red[4][64][20];
  int tid = threadIdx.x;
  int w = tid>>6, l = tid&63, lm = l&15, lq = l>>4;
  f32x4 acc0={0,0,0,0}, acc1={0,0,0,0}, acc2={0,0,0,0}, acc3={0,0,0,0};
  int readmode = (blockIdx.x < 64);
  int tile = readmode ? blockIdx.x : (blockIdx.x - 64);
  int ncol = tile*16 + lm;
  const float* wp = readmode ? (Wread + (size_t)ncol*3072 + lq*8)
                             : (Whh   + (size_t)ncol*1024 + lq*8);
  const short* ap = readmode ? (X_b + lm*4096 + lq*8)
                             : (X_b + 1024 + lm*4096 + lq*8);
  int kbeg = readmode ? w*768 : w*256;
  int kend = readmode ? (kbeg + 768) : (kbeg + 256);
  for(int k0=kbeg; k0<kend; k0+=64){
    f4 w0 = *(const f4*)(wp + k0);
    f4 w1 = *(const f4*)(wp + k0 + 4);
    f4 w2 = *(const f4*)(wp + k0 + 32);
    f4 w3 = *(const f4*)(wp + k0 + 36);
    bf16x8 a00 = *(const bf16x8*)(ap + k0);
    bf16x8 a01 = *(const bf16x8*)(ap + k0 + 32);
    bf16x8 a10 = *(const bf16x8*)(ap + 16*4096 + k0);
    bf16x8 a11 = *(const bf16x8*)(ap + 16*4096 + k0 + 32);
    bf16x8 a20 = *(const bf16x8*)(ap + 32*4096 + k0);
    bf16x8 a21 = *(const bf16x8*)(ap + 32*4096 + k0 + 32);
    bf16x8 a30 = *(const bf16x8*)(ap + 48*4096 + k0);
    bf16x8 a31 = *(const bf16x8*)(ap + 48*4096 + k0 + 32);
    bf16x8 b0 = pack8(w0,w1), b1 = pack8(w2,w3);
    acc0 = mfma16(a00,b0,acc0); acc1 = mfma16(a10,b0,acc1);
    acc2 = mfma16(a20,b0,acc2); acc3 = mfma16(a30,b0,acc3);
    acc0 = mfma16(a01,b1,acc0); acc1 = mfma16(a11,b1,acc1);
    acc2 = mfma16(a21,b1,acc2); acc3 = mfma16(a31,b1,acc3);
  }
  #pragma unroll
  for(int r=0;r<4;r++){
    red[w][     lq*4+r][lm] = acc0[r];
    red[w][16 + lq*4+r][lm] = acc1[r];
    red[w][32 + lq*4+r][lm] = acc2[r];
    red[w][48 + lq*4+r][lm] = acc3[r];
  }
  __syncthreads();
  int m = tid>>2;
  if(readmode){
    int ie = iemo[m];
    #pragma unroll
    for(int j=0;j<4;j++){
      int c = (tid&3)*4 + j;
      float v = red[0][m][c]+red[1][m][c]+red[2][m][c]+red[3][m][c];
      int n = tile*16 + c;
      float s = sigm(v + bread[n]);
      float eg = s * eemb[(size_t)ie*1024 + n];
      emog[(size_t)m*1024 + n] = eg;
      X_b_w[(size_t)m*4096 + 3072 + n] = f2bf(eg);
    }
  } else {
    #pragma unroll
    for(int j=0;j<4;j++){
      int c = (tid&3)*4 + j;
      float v = red[0][m][c]+red[1][m][c]+red[2][m][c]+red[3][m][c];
      gh[(size_t)m*3072 + tile*16 + c] = v;
    }
  }
}

// ---- 3: gi partials = X @ W_ih^T, 2-way K-split (grid (192,2)) ----
__launch_bounds__(256)
__global__ void k_gi(const short* __restrict__ X_b, const float* __restrict__ Wih,
                     float* __restrict__ gp){
  __shared__ float red[4][64][20];
  int tid = threadIdx.x;
  int w = tid>>6, l = tid&63, lm = l&15, lq = l>>4;
  int half = blockIdx.y;
  int ncol = blockIdx.x*16 + lm;
  const float* wp = Wih + (size_t)ncol*4096 + lq*8;
  const short* ap = X_b + lm*4096 + lq*8;
  int kbeg = half*2048 + w*512, kend = kbeg + 512;
  f32x4 acc0={0,0,0,0}, acc1={0,0,0,0}, acc2={0,0,0,0}, acc3={0,0,0,0};
  for(int k0=kbeg; k0<kend; k0+=64){
    f4 w0 = *(const f4*)(wp + k0);
    f4 w1 = *(const f4*)(wp + k0 + 4);
    f4 w2 = *(const f4*)(wp + k0 + 32);
    f4 w3 = *(const f4*)(wp + k0 + 36);
    bf16x8 a00 = *(const bf16x8*)(ap + k0);
    bf16x8 a01 = *(const bf16x8*)(ap + k0 + 32);
    bf16x8 a10 = *(const bf16x8*)(ap + 16*4096 + k0);
    bf16x8 a11 = *(const bf16x8*)(ap + 16*4096 + k0 + 32);
    bf16x8 a20 = *(const bf16x8*)(ap + 32*4096 + k0);
    bf16x8 a21 = *(const bf16x8*)(ap + 32*4096 + k0 + 32);
    bf16x8 a30 = *(const bf16x8*)(ap + 48*4096 + k0);
    bf16x8 a31 = *(const bf16x8*)(ap + 48*4096 + k0 + 32);
    bf16x8 b0 = pack8(w0,w1), b1 = pack8(w2,w3);
    acc0 = mfma16(a00,b0,acc0); acc1 = mfma16(a10,b0,acc1);
    acc2 = mfma16(a20,b0,acc2); acc3 = mfma16(a30,b0,acc3);
    acc0 = mfma16(a01,b1,acc0); acc1 = mfma16(a11,b1,acc1);
    acc2 = mfma16(a21,b1,acc2); acc3 = mfma16(a31,b1,acc3);
  }
  #pragma unroll
  for(int r=0;r<4;r++){
    red[w][     lq*4+r][lm] = acc0[r];
    red[w][16 + lq*4+r][lm] = acc1[r];
    red[w][32 + lq*4+r][lm] = acc2[r];
    red[w][48 + lq*4+r][lm] = acc3[r];
  }
  __syncthreads();
  int m = tid>>2;
  #pragma unroll
  for(int j=0;j<4;j++){
    int c = (tid&3)*4 + j;
    float v = red[0][m][c]+red[1][m][c]+red[2][m][c]+red[3][m][c];
    gp[(size_t)(half*64+m)*3072 + blockIdx.x*16 + c] = v;
  }
}

// ---- 4: GRU elementwise (sums 2 gi partials + biases) ----
__global__ void k_gru(const float* __restrict__ gp, const float* __restrict__ gh,
                      const float* __restrict__ bih, const float* __restrict__ bhh,
                      const float* __restrict__ h0, float* __restrict__ hid,
                      short* __restrict__ hid_b, short* __restrict__ a2_b){
  int t = blockIdx.x*256 + threadIdx.x;   // 16384
  int b = t>>8, j = (t&255)*4;
  const float* gi0 = gp + (size_t)b*3072 + j;
  const float* gi1 = gp + (size_t)(64+b)*3072 + j;
  const float* ghb = gh + (size_t)b*3072 + j;
  f4 h0v = *(const f4*)(h0 + (size_t)b*1024 + j);
  f4 hres; short4 hb;
  #pragma unroll
  for(int c=0;c<4;c++){
    float r = sigm(gi0[c]      + gi1[c]      + bih[j+c]      + ghb[c]      + bhh[j+c]);
    float z = sigm(gi0[1024+c] + gi1[1024+c] + bih[1024+j+c] + ghb[1024+c] + bhh[1024+j+c]);
    float n = tanhf(gi0[2048+c] + gi1[2048+c] + bih[2048+j+c] + r*(ghb[2048+c] + bhh[2048+j+c]));
    float hv = ((const float*)&h0v)[c];
    float h = (1.0f - z)*n + z*hv;
    ((float*)&hres)[c] = h;
    ((short*)&hb)[c] = f2bf(h);
  }
  *(f4*)(hid + (size_t)b*1024 + j) = hres;
  *(short4*)(hid_b + (size_t)b*1024 + j) = hb;
  *(short4*)(a2_b + (size_t)b*2048 + j) = hb;
}

// ---- 5: blocks 0..511: flash attention; 512..575: W_write gemm;
//         576..1361: W_out f32 -> bf16 streaming conversion ----
__launch_bounds__(256)
__global__ void k_flash(const float* __restrict__ enc, const float* __restrict__ hid,
                        float* __restrict__ part, float* __restrict__ ml,
                        const short* __restrict__ hid_b,
                        const float* __restrict__ Wwrite, const float* __restrict__ bwrite,
                        const float* __restrict__ emog, float* __restrict__ memo,
                        const float* __restrict__ Wout, short* __restrict__ wb){
  __shared__ float red[4][64][20];
  int tid = threadIdx.x;
  int w = tid>>6, l = tid&63;
  if(blockIdx.x < 512){
    int b = blockIdx.x>>3, c = blockIdx.x&7;
    int chunk = c*4 + w;
    const float* hp = hid + (size_t)b*1024 + l*16;
    f4 q0 = *(const f4*)(hp), q1 = *(const f4*)(hp+4);
    f4 q2 = *(const f4*)(hp+8), q3 = *(const f4*)(hp+12);
    f4 cx0={0,0,0,0}, cx1={0,0,0,0}, cx2={0,0,0,0}, cx3={0,0,0,0};
    float mx = -1e30f, ls = 0.0f;
    int s0 = c*32 + w*8;
    for(int si=0; si<8; si++){
      const float* ep = enc + ((size_t)(s0+si)*64 + b)*1024 + l*16;
      f4 e0 = *(const f4*)(ep),   e1 = *(const f4*)(ep+4);
      f4 e2 = *(const f4*)(ep+8), e3 = *(const f4*)(ep+12);
      float d = e0.x*q0.x + e0.y*q0.y + e0.z*q0.z + e0.w*q0.w
              + e1.x*q1.x + e1.y*q1.y + e1.z*q1.z + e1.w*q1.w
              + e2.x*q2.x + e2.y*q2.y + e2.z*q2.z + e2.w*q2.w
              + e3.x*q3.x + e3.y*q3.y + e3.z*q3.z + e3.w*q3.w;
      d = wrsum(d);
      float mn = fmaxf(mx, d);
      float a = expf(mx - mn), p = expf(d - mn);
      ls = ls*a + p;
      cx0.x = cx0.x*a + p*e0.x; cx0.y = cx0.y*a + p*e0.y;
      cx0.z = cx0.z*a + p*e0.z; cx0.w = cx0.w*a + p*e0.w;
      cx1.x = cx1.x*a + p*e1.x; cx1.y = cx1.y*a + p*e1.y;
      cx1.z = cx1.z*a + p*e1.z; cx1.w = cx1.w*a + p*e1.w;
      cx2.x = cx2.x*a + p*e2.x; cx2.y = cx2.y*a + p*e2.y;
      cx2.z = cx2.z*a + p*e2.z; cx2.w = cx2.w*a + p*e2.w;
      cx3.x = cx3.x*a + p*e3.x; cx3.y = cx3.y*a + p*e3.y;
      cx3.z = cx3.z*a + p*e3.z; cx3.w = cx3.w*a + p*e3.w;
      mx = mn;
    }
    float* pp = part + ((size_t)b*32 + chunk)*1024 + l*16;
    *(f4*)(pp)    = cx0; *(f4*)(pp+4)  = cx1;
    *(f4*)(pp+8)  = cx2; *(f4*)(pp+12) = cx3;
    if(l==0){ ml[((size_t)b*32+chunk)*2] = mx; ml[((size_t)b*32+chunk)*2+1] = ls; }
  } else if(blockIdx.x < 576){
    int tile = blockIdx.x - 512;
    int lm = l&15, lq = l>>4;
    int ncol = tile*16 + lm;
    const float* wp = Wwrite + (size_t)ncol*1024 + lq*8;
    const short* ap = hid_b + lm*1024 + lq*8;
    int kbeg = w*256, kend = kbeg + 256;
    f32x4 acc0={0,0,0,0}, acc1={0,0,0,0}, acc2={0,0,0,0}, acc3={0,0,0,0};
    for(int k0=kbeg; k0<kend; k0+=64){
      f4 w0 = *(const f4*)(wp + k0);
      f4 w1 = *(const f4*)(wp + k0 + 4);
      f4 w2 = *(const f4*)(wp + k0 + 32);
      f4 w3 = *(const f4*)(wp + k0 + 36);
      bf16x8 a00 = *(const bf16x8*)(ap + k0);
      bf16x8 a01 = *(const bf16x8*)(ap + k0 + 32);
      bf16x8 a10 = *(const bf16x8*)(ap + 16*1024 + k0);
      bf16x8 a11 = *(const bf16x8*)(ap + 16*1024 + k0 + 32);
      bf16x8 a20 = *(const bf16x8*)(ap + 32*1024 + k0);
      bf16x8 a21 = *(const bf16x8*)(ap + 32*1024 + k0 + 32);
      bf16x8 a30 = *(const bf16x8*)(ap + 48*1024 + k0);
      bf16x8 a31 = *(const bf16x8*)(ap + 48*1024 + k0 + 32);
      bf16x8 b0 = pack8(w0,w1), b1 = pack8(w2,w3);
      acc0 = mfma16(a00,b0,acc0); acc1 = mfma16(a10,b0,acc1);
      acc2 = mfma16(a20,b0,acc2); acc3 = mfma16(a30,b0,acc3);
      acc0 = mfma16(a01,b1,acc0); acc1 = mfma16(a11,b1,acc1);
      acc2 = mfma16(a21,b1,acc2); acc3 = mfma16(a31,b1,acc3);
    }
    #pragma unroll
    for(int r=0;r<4;r++){
      red[w][     lq*4+r][lm] = acc0[r];
      red[w][16 + lq*4+r][lm] = acc1[r];
      red[w][32 + lq*4+r][lm] = acc2[r];
      red[w][48 + lq*4+r][lm] = acc3[r];
    }
    __syncthreads();
    int m = tid>>2;
    #pragma unroll
    for(int j=0;j<4;j++){
      int c = (tid&3)*4 + j;
      float v = red[0][m][c]+red[1][m][c]+red[2][m][c]+red[3][m][c];
      int n = tile*16 + c;
      memo[(size_t)m*1024 + n] = sigm(v + bwrite[n]) * emog[(size_t)m*1024 + n];
    }
  } else {
    // convert 64 rows of W_out to bf16 (fully coalesced stream)
    int tile = blockIdx.x - 576;          // 0..785
    const float* src = Wout + (size_t)tile*65536;
    short* dst = wb + (size_t)tile*65536;
    int rbase = tile*64;
    #pragma unroll 4
    for(int i=0;i<64;i++){
      int j = i*256 + tid;                // f4-chunk index, 0..16383
      int row = rbase + (j>>8);
      if(row < V){
        f4 v = *(const f4*)(src + (size_t)j*4);
        *(short4*)(dst + (size_t)j*4) =
            make_short4(f2bf(v.x),f2bf(v.y),f2bf(v.z),f2bf(v.w));
      }
    }
  }
}

// ---- 6: merge 32 chunk partials -> context f32 (output) + a2_b[:, 1024:] bf16 ----
__global__ void k_ctxr(const float* __restrict__ part, const float* __restrict__ ml,
                       float* __restrict__ ctxo, short* __restrict__ a2_b){
  int b = blockIdx.x; int t = threadIdx.x;
  __shared__ float sscale[32];
  if(t < 64){
    float mc = (t<32) ? ml[((size_t)b*32+t)*2]   : -1e30f;
    float lc = (t<32) ? ml[((size_t)b*32+t)*2+1] : 0.0f;
    float M = wrmax(mc);
    float L = wrsum(lc * expf(mc - M));
    if(t<32) sscale[t] = expf(mc - M) / L;
  }
  __syncthreads();
  int h = t*4;
  f4 acc = {0,0,0,0};
  for(int c=0;c<32;c++){
    f4 p = *(const f4*)(part + ((size_t)b*32 + c)*1024 + h);
    float s = sscale[c];
    acc.x += s*p.x; acc.y += s*p.y; acc.z += s*p.z; acc.w += s*p.w;
  }
  *(f4*)(ctxo + (size_t)b*1024 + h) = acc;
  *(short4*)(a2_b + (size_t)b*2048 + 1024 + h) =
      make_short4(f2bf(acc.x),f2bf(acc.y),f2bf(acc.z),f2bf(acc.w));
}

// ---- 7: concat_out = tanh(a2 @ W_concat^T + b) -> cc_b bf16 ----
__launch_bounds__(256)
__global__ void k_cc(const short* __restrict__ a2_b, const float* __restrict__ Wc,
                     const float* __restrict__ bc, short* __restrict__ cc_b){
  __shared__ float red[4][64][20];
  int tid = threadIdx.x;
  int w = tid>>6, l = tid&63, lm = l&15, lq = l>>4;
  int ncol = blockIdx.x*16 + lm;
  const float* wp = Wc + (size_t)ncol*2048 + lq*8;
  const short* ap = a2_b + lm*2048 + lq*8;
  int kbeg = w*512, kend = kbeg + 512;
  f32x4 acc0={0,0,0,0}, acc1={0,0,0,0}, acc2={0,0,0,0}, acc3={0,0,0,0};
  for(int k0=kbeg; k0<kend; k0+=64){
    f4 w0 = *(const f4*)(wp + k0);
    f4 w1 = *(const f4*)(wp + k0 + 4);
    f4 w2 = *(const f4*)(wp + k0 + 32);
    f4 w3 = *(const f4*)(wp + k0 + 36);
    bf16x8 a00 = *(const bf16x8*)(ap + k0);
    bf16x8 a01 = *(const bf16x8*)(ap + k0 + 32);
    bf16x8 a10 = *(const bf16x8*)(ap + 16*2048 + k0);
    bf16x8 a11 = *(const bf16x8*)(ap + 16*2048 + k0 + 32);
    bf16x8 a20 = *(const bf16x8*)(ap + 32*2048 + k0);
    bf16x8 a21 = *(const bf16x8*)(ap + 32*2048 + k0 + 32);
    bf16x8 a30 = *(const bf16x8*)(ap + 48*2048 + k0);
    bf16x8 a31 = *(const bf16x8*)(ap + 48*2048 + k0 + 32);
    bf16x8 b0 = pack8(w0,w1), b1 = pack8(w2,w3);
    acc0 = mfma16(a00,b0,acc0); acc1 = mfma16(a10,b0,acc1);
    acc2 = mfma16(a20,b0,acc2); acc3 = mfma16(a30,b0,acc3);
    acc0 = mfma16(a01,b1,acc0); acc1 = mfma16(a11,b1,acc1);
    acc2 = mfma16(a21,b1,acc2); acc3 = mfma16(a31,b1,acc3);
  }
  #pragma unroll
  for(int r=0;r<4;r++){
    red[w][     lq*4+r][lm] = acc0[r];
    red[w][16 + lq*4+r][lm] = acc1[r];
    red[w][32 + lq*4+r][lm] = acc2[r];
    red[w][48 + lq*4+r][lm] = acc3[r];
  }
  __syncthreads();
  int m = tid>>2;
  #pragma unroll
  for(int j=0;j<4;j++){
    int c = (tid&3)*4 + j;
    float v = red[0][m][c]+red[1][m][c]+red[2][m][c]+red[3][m][c];
    int n = blockIdx.x*16 + c;
    cc_b[(size_t)m*1024 + n] = f2bf(tanhf(v + bc[n]));
  }
}

// ---- 8: logits = cc @ Wb(bf16)^T + b_out, 512 threads, 2-way K-split,
//         fused per-block row stats ----
__launch_bounds__(512)
__global__ void k_out(const short* __restrict__ A, const short* __restrict__ Wb,
                      const float* __restrict__ bias, const float* __restrict__ wal,
                      const int* __restrict__ mem,
                      float* __restrict__ outf, float* __restrict__ pstat){
  __shared__ float red[4][64][20];   // K-combine buffer (per col-group)
  __shared__ float sst[4][64][6];    // per col-group per-row stats
  int tid = threadIdx.x;
  int w = tid>>6, l = tid&63;
  int lm = l&15, lq = l>>4;
  int cg = w&3, half = w>>2;
  int ncol = blockIdx.x*64 + cg*16 + lm;
  int nrow = ncol < V ? ncol : V-1;
  const short* wp = Wb + (size_t)nrow*1024 + lq*8;
  const short* ap = A + lm*1024 + lq*8;
  int kbeg = half*512, kend = kbeg + 512;
  f32x4 acc0={0,0,0,0}, acc1={0,0,0,0}, acc2={0,0,0,0}, acc3={0,0,0,0};
  for(int k0=kbeg; k0<kend; k0+=64){
    bf16x8 b0 = *(const bf16x8*)(wp + k0);
    bf16x8 b1 = *(const bf16x8*)(wp + k0 + 32);
    bf16x8 a00 = *(const bf16x8*)(ap + k0);
    bf16x8 a01 = *(const bf16x8*)(ap + k0 + 32);
    bf16x8 a10 = *(const bf16x8*)(ap + 16*1024 + k0);
    bf16x8 a11 = *(const bf16x8*)(ap + 16*1024 + k0 + 32);
    bf16x8 a20 = *(const bf16x8*)(ap + 32*1024 + k0);
    bf16x8 a21 = *(const bf16x8*)(ap + 32*1024 + k0 + 32);
    bf16x8 a30 = *(const bf16x8*)(ap + 48*1024 + k0);
    bf16x8 a31 = *(const bf16x8*)(ap + 48*1024 + k0 + 32);
    acc0 = mfma16(a00,b0,acc0); acc1 = mfma16(a10,b0,acc1);
    acc2 = mfma16(a20,b0,acc2); acc3 = mfma16(a30,b0,acc3);
    acc0 = mfma16(a01,b1,acc0); acc1 = mfma16(a11,b1,acc1);
    acc2 = mfma16(a21,b1,acc2); acc3 = mfma16(a31,b1,acc3);
  }
  if(half==1){
    #pragma unroll
    for(int r=0;r<4;r++){
      red[cg][     lq*4+r][lm] = acc0[r];
      red[cg][16 + lq*4+r][lm] = acc1[r];
      red[cg][32 + lq*4+r][lm] = acc2[r];
      red[cg][48 + lq*4+r][lm] = acc3[r];
    }
  }
  __syncthreads();
  if(half==0){
    #pragma unroll
    for(int r=0;r<4;r++){
      acc0[r] += red[cg][     lq*4+r][lm];
      acc1[r] += red[cg][16 + lq*4+r][lm];
      acc2[r] += red[cg][32 + lq*4+r][lm];
      acc3[r] += red[cg][48 + lq*4+r][lm];
    }
    float bv=0.0f, wv=0.0f; int mv=-1;
    if(ncol < V){ bv = bias[ncol]; wv = wal[ncol]; mv = mem[ncol]; }
    #pragma unroll
    for(int qi=0; qi<4; qi++){
      #pragma unroll
      for(int r=0;r<4;r++){
        float v;
        if(qi==0) v = acc0[r]+bv; else if(qi==1) v = acc1[r]+bv;
        else if(qi==2) v = acc2[r]+bv; else v = acc3[r]+bv;
        int row = lq*4 + r + 16*qi;
        if(ncol < V) outf[(size_t)row*V + ncol] = v;
        float dd = v*wv;
        float em = (mv==1) ? v : -1e30f;
        float gm = (mv==0) ? v : -1e30f;
        #pragma unroll
        for(int o=1;o<16;o<<=1){
          dd += __shfl_xor(dd,o);
          em = fmaxf(em, __shfl_xor(em,o));
          gm = fmaxf(gm, __shfl_xor(gm,o));
        }
        float pe = (mv==1) ? expf(v - em) : 0.0f;
        float pg = (mv==0) ? expf(v - gm) : 0.0f;
        #pragma unroll
        for(int o=1;o<16;o<<=1){
          pe += __shfl_xor(pe,o);
          pg += __shfl_xor(pg,o);
        }
        if(lm==0){
          sst[cg][row][0]=dd; sst[cg][row][1]=em; sst[cg][row][2]=pe;
          sst[cg][row][3]=gm; sst[cg][row][4]=pg;
        }
      }
    }
  }
  __syncthreads();
  if(tid < 64){
    float dd=0.0f, me=-1e30f, se=0.0f, mg=-1e30f, sg=0.0f;
    #pragma unroll
    for(int g=0; g<4; g++){
      dd += sst[g][tid][0];
      float m2=sst[g][tid][1], s2=sst[g][tid][2];
      float nm=fmaxf(me,m2); se = se*expf(me-nm) + s2*expf(m2-nm); me = nm;
      m2=sst[g][tid][3]; s2=sst[g][tid][4];
      nm=fmaxf(mg,m2); sg = sg*expf(mg-nm) + s2*expf(m2-nm); mg = nm;
    }
    float* pp = pstat + ((size_t)tid*NBLK + blockIdx.x)*6;
    pp[0]=dd; pp[1]=me; pp[2]=se; pp[3]=mg; pp[4]=sg;
  }
}

// ---- 9: merge per-block stats partials -> stats[b][8] ----
__global__ void k_merge(const float* __restrict__ pstat, float* __restrict__ stats){
  int b = blockIdx.x, t = threadIdx.x;
  float dd=0.0f, me=-1e30f, se=0.0f, mg=-1e30f, sg=0.0f;
  for(int i=t; i<NBLK; i+=256){
    const float* pp = pstat + ((size_t)b*NBLK + i)*6;
    dd += pp[0];
    float m2=pp[1], s2=pp[2];
    float nm=fmaxf(me,m2); se = se*expf(me-nm) + s2*expf(m2-nm); me = nm;
    m2=pp[3]; s2=pp[4];
    nm=fmaxf(mg,m2); sg = sg*expf(mg-nm) + s2*expf(m2-nm); mg = nm;
  }
  #pragma unroll
  for(int o=32;o;o>>=1){
    dd += __shfl_xor(dd,o);
    float m2=__shfl_xor(me,o), s2=__shfl_xor(se,o);
    float nm=fmaxf(me,m2); se = se*expf(me-nm) + s2*expf(m2-nm); me = nm;
    m2=__shfl_xor(mg,o); s2=__shfl_xor(sg,o);
    nm=fmaxf(mg,m2); sg = sg*expf(mg-nm) + s2*expf(m2-nm); mg = nm;
  }
  __shared__ float sm[4][5];
  int wv = t>>6;
  if((t&63)==0){ sm[wv][0]=dd; sm[wv][1]=me; sm[wv][2]=se; sm[wv][3]=mg; sm[wv][4]=sg; }
  __syncthreads();
  if(t==0){
    float D=0, M=-1e30f, S=0, M2=-1e30f, S2=0;
    for(int i=0;i<4;i++){
      D += sm[i][0];
      float m = fmaxf(M, sm[i][1]); S  = S*expf(M-m)  + sm[i][2]*expf(sm[i][1]-m);  M = m;
      float n = fmaxf(M2,sm[i][3]); S2 = S2*expf(M2-n)+ sm[i][4]*expf(sm[i][3]-n); M2 = n;
    }
    stats[b*8+0]=D; stats[b*8+1]=M; stats[b*8+2]=M2; stats[b*8+3]=S; stats[b*8+4]=S2;
  }
}

// ---- 10: dual gated softmax in-place ----
__global__ void k_final(float* __restrict__ logits, const int* __restrict__ mem,
                        const float* __restrict__ stats, const float* __restrict__ balpha){
  int v = blockIdx.x*256 + threadIdx.x;
  int b = blockIdx.y;
  if(v >= V) return;
  float dot = stats[b*8+0], me = stats[b*8+1], mg = stats[b*8+2];
  float se = stats[b*8+3],  sg = stats[b*8+4];
  float g = sigm(dot + balpha[0]);
  float l = logits[(size_t)b*V + v];
  float o = (mem[v]==1) ? (expf(l-me)/se * g) : (expf(l-mg)/sg * (1.0f-g));
  logits[(size_t)b*V + v] = o;
}

extern "C" void kernel_launch(void* const* d_in, const int* in_sizes, int n_in,
                              void* d_out, int out_size, void* d_ws, size_t ws_size,
                              hipStream_t stream){
  const int*   istep   = (const int*)d_in[0];
  const int*   iemo    = (const int*)d_in[1];
  const float* lasth   = (const float*)d_in[2];
  const float* ictx    = (const float*)d_in[3];
  const float* enc     = (const float*)d_in[4];
  const int*   emem    = (const int*)d_in[5];
  const float* emb     = (const float*)d_in[6];
  const float* eemb    = (const float*)d_in[7];
  const float* W_read  = (const float*)d_in[8];
  const float* b_read  = (const float*)d_in[9];
  const float* W_write = (const float*)d_in[10];
  const float* b_write = (const float*)d_in[11];
  const float* W_ih    = (const float*)d_in[12];
  const float* W_hh    = (const float*)d_in[13];
  const float* b_ih    = (const float*)d_in[14];
  const float* b_hh    = (const float*)d_in[15];
  const float* W_concat= (const float*)d_in[16];
  const float* b_concat= (const float*)d_in[17];
  const float* W_out   = (const float*)d_in[18];
  const float* b_out   = (const float*)d_in[19];
  const float* W_alpha = (const float*)d_in[20];
  const float* b_alpha = (const float*)d_in[21];

  short* X_b  = (short*)d_ws;                           // 64x4096 bf16
  float* emog = (float*)((char*)d_ws + 524288);         // 64x1024
  float* gp   = emog + 65536;                           // 2x64x3072 (gi partials)
  float* gh   = gp + 393216;                            // 64x3072
  float* part = gh + 196608;                            // 64x32x1024
  float* ml   = part + 2097152;                         // 64x32x2
  float* stats= ml + 4096;                              // 512
  float* pstat= stats + 512;                            // 64x786x6
  short* hid_b= (short*)(pstat + 64*NBLK*6);            // 64x1024 bf16
  short* a2_b = hid_b + 65536;                          // 64x2048 bf16
  short* cc_b = a2_b + 131072;                          // 64x1024 bf16
  short* wb   = cc_b + 65536;                           // 786*64*1024 bf16 (103 MB)

  float* out0 = (float*)d_out;          // [64][V]
  float* hid  = out0 + (size_t)B*V;     // [64][1024] (output: hidden)
  float* memo = hid + 65536;            // [64][1024] (output: new_M_emo)
  float* ctxo = memo + 65536;           // [64][1024] (output: context)

  k_build<<<64,256,0,stream>>>(istep, lasth, ictx, emb, X_b);
  k_pre  <<<256,256,0,stream>>>(iemo, X_b, eemb, W_read, b_read, W_hh, emog, X_b, gh);
  k_gi   <<<dim3(192,2),256,0,stream>>>(X_b, W_ih, gp);
  k_gru  <<<64,256,0,stream>>>(gp, gh, b_ih, b_hh, lasth, hid, hid_b, a2_b);
  k_flash<<<576+NBLK,256,0,stream>>>(enc, hid, part, ml, hid_b, W_write, b_write,
                                     emog, memo, W_out, wb);
  k_ctxr <<<64,256,0,stream>>>(part, ml, ctxo, a2_b);
  k_cc   <<<64,256,0,stream>>>(a2_b, W_concat, b_concat, cc_b);
  k_out  <<<NBLK,512,0,stream>>>(cc_b, wb, b_out, W_alpha, emem, out0, pstat);
  k_merge<<<64,256,0,stream>>>(pstat, stats);
  k_final<<<dim3(197,64),256,0,stream>>>(out0, emem, stats, b_alpha);
}

// Round 11
// 238.981 us; speedup vs baseline: 1.2671x; 1.0951x over previous
//
#include <hip/hip_runtime.h>
#include <hip/hip_bf16.h>
#include <math.h>

#define B 64
#define H 1024
#define SEQ 256
#define V 50257
#define NBLK 786   // ceil(V/64)

typedef float4 f4;
typedef __attribute__((ext_vector_type(4))) float f32x4;
typedef __attribute__((ext_vector_type(8))) short bf16x8;

__device__ inline float sigm(float x){ return 1.0f/(1.0f+expf(-x)); }
__device__ inline short f2bf(float x){
  __hip_bfloat16 h = __float2bfloat16(x);
  union { __hip_bfloat16 h; short s; } u; u.h = h; return u.s;
}
__device__ inline short2 cvt2(float x, float y){
  __hip_bfloat162 h = __float22bfloat162_rn(float2{x, y});
  union { __hip_bfloat162 h; short2 s; } u; u.h = h; return u.s;
}
__device__ inline bf16x8 pack8(f4 lo, f4 hi){
  union { bf16x8 v; short2 s[4]; } u;
  u.s[0]=cvt2(lo.x,lo.y); u.s[1]=cvt2(lo.z,lo.w);
  u.s[2]=cvt2(hi.x,hi.y); u.s[3]=cvt2(hi.z,hi.w);
  return u.v;
}
__device__ inline float wrsum(float v){
  #pragma unroll
  for(int o=32;o;o>>=1) v += __shfl_xor(v,o);
  return v;
}
__device__ inline float wrmax(float v){
  #pragma unroll
  for(int o=32;o;o>>=1) v = fmaxf(v,__shfl_xor(v,o));
  return v;
}
__device__ inline f32x4 mfma16(bf16x8 a, bf16x8 b, f32x4 c){
  return __builtin_amdgcn_mfma_f32_16x16x32_bf16(a,b,c,0,0,0);
}

// ---- 1: build X_b[:, :3072] = bf16[emb(iw) | lasth | ictx] ----
__global__ void k_build(const int* __restrict__ istep,
                        const float* __restrict__ lasth, const float* __restrict__ ictx,
                        const float* __restrict__ emb, short* __restrict__ X_b){
  int b = blockIdx.x; int h = threadIdx.x*4;
  int iw = istep[b];
  f4 lw = *(const f4*)(emb  + (size_t)iw*H + h);
  f4 hs = *(const f4*)(lasth + (size_t)b*H + h);
  f4 cv = *(const f4*)(ictx + (size_t)b*H + h);
  short* xb = X_b + (size_t)b*4096;
  *(short4*)(xb +        h) = make_short4(f2bf(lw.x),f2bf(lw.y),f2bf(lw.z),f2bf(lw.w));
  *(short4*)(xb + 1024 + h) = make_short4(f2bf(hs.x),f2bf(hs.y),f2bf(hs.z),f2bf(hs.w));
  *(short4*)(xb + 2048 + h) = make_short4(f2bf(cv.x),f2bf(cv.y),f2bf(cv.z),f2bf(cv.w));
}

// ---- 2: blocks 0..63: W_read gemm + sigmoid*eemb -> emog f32 + X_b[:,3072:] bf16
//         blocks 64..255: W_hh gemm (192 tiles) -> gh raw f32 ----
__launch_bounds__(256)
__global__ void k_pre(const int* __restrict__ iemo, const short* __restrict__ X_b,
                      const float* __restrict__ eemb,
                      const float* __restrict__ Wread, const float* __restrict__ bread,
                      const float* __restrict__ Whh,
                      float* __restrict__ emog, short* __restrict__ X_b_w,
                      float* __restrict__ gh){
  __shared__ float red[4][64][20];
  int tid = threadIdx.x;
  int w = tid>>6, l = tid&63, lm = l&15, lq = l>>4;
  f32x4 acc0={0,0,0,0}, acc1={0,0,0,0}, acc2={0,0,0,0}, acc3={0,0,0,0};
  int readmode = (blockIdx.x < 64);
  int tile = readmode ? blockIdx.x : (blockIdx.x - 64);
  int ncol = tile*16 + lm;
  const float* wp = readmode ? (Wread + (size_t)ncol*3072 + lq*8)
                             : (Whh   + (size_t)ncol*1024 + lq*8);
  const short* ap = readmode ? (X_b + lm*4096 + lq*8)
                             : (X_b + 1024 + lm*4096 + lq*8);
  int kbeg = readmode ? w*768 : w*256;
  int kend = readmode ? (kbeg + 768) : (kbeg + 256);
  for(int k0=kbeg; k0<kend; k0+=64){
    f4 w0 = *(const f4*)(wp + k0);
    f4 w1 = *(const f4*)(wp + k0 + 4);
    f4 w2 = *(const f4*)(wp + k0 + 32);
    f4 w3 = *(const f4*)(wp + k0 + 36);
    bf16x8 a00 = *(const bf16x8*)(ap + k0);
    bf16x8 a01 = *(const bf16x8*)(ap + k0 + 32);
    bf16x8 a10 = *(const bf16x8*)(ap + 16*4096 + k0);
    bf16x8 a11 = *(const bf16x8*)(ap + 16*4096 + k0 + 32);
    bf16x8 a20 = *(const bf16x8*)(ap + 32*4096 + k0);
    bf16x8 a21 = *(const bf16x8*)(ap + 32*4096 + k0 + 32);
    bf16x8 a30 = *(const bf16x8*)(ap + 48*4096 + k0);
    bf16x8 a31 = *(const bf16x8*)(ap + 48*4096 + k0 + 32);
    bf16x8 b0 = pack8(w0,w1), b1 = pack8(w2,w3);
    acc0 = mfma16(a00,b0,acc0); acc1 = mfma16(a10,b0,acc1);
    acc2 = mfma16(a20,b0,acc2); acc3 = mfma16(a30,b0,acc3);
    acc0 = mfma16(a01,b1,acc0); acc1 = mfma16(a11,b1,acc1);
    acc2 = mfma16(a21,b1,acc2); acc3 = mfma16(a31,b1,acc3);
  }
  #pragma unroll
  for(int r=0;r<4;r++){
    red[w][     lq*4+r][lm] = acc0[r];
    red[w][16 + lq*4+r][lm] = acc1[r];
    red[w][32 + lq*4+r][lm] = acc2[r];
    red[w][48 + lq*4+r][lm] = acc3[r];
  }
  __syncthreads();
  int m = tid>>2;
  if(readmode){
    int ie = iemo[m];
    #pragma unroll
    for(int j=0;j<4;j++){
      int c = (tid&3)*4 + j;
      float v = red[0][m][c]+red[1][m][c]+red[2][m][c]+red[3][m][c];
      int n = tile*16 + c;
      float s = sigm(v + bread[n]);
      float eg = s * eemb[(size_t)ie*1024 + n];
      emog[(size_t)m*1024 + n] = eg;
      X_b_w[(size_t)m*4096 + 3072 + n] = f2bf(eg);
    }
  } else {
    #pragma unroll
    for(int j=0;j<4;j++){
      int c = (tid&3)*4 + j;
      float v = red[0][m][c]+red[1][m][c]+red[2][m][c]+red[3][m][c];
      gh[(size_t)m*3072 + tile*16 + c] = v;
    }
  }
}

// ---- 3: gi partials = X @ W_ih^T, 2-way K-split (grid (192,2)) ----
__launch_bounds__(256)
__global__ void k_gi(const short* __restrict__ X_b, const float* __restrict__ Wih,
                     float* __restrict__ gp){
  __shared__ float red[4][64][20];
  int tid = threadIdx.x;
  int w = tid>>6, l = tid&63, lm = l&15, lq = l>>4;
  int half = blockIdx.y;
  int ncol = blockIdx.x*16 + lm;
  const float* wp = Wih + (size_t)ncol*4096 + lq*8;
  const short* ap = X_b + lm*4096 + lq*8;
  int kbeg = half*2048 + w*512, kend = kbeg + 512;
  f32x4 acc0={0,0,0,0}, acc1={0,0,0,0}, acc2={0,0,0,0}, acc3={0,0,0,0};
  for(int k0=kbeg; k0<kend; k0+=64){
    f4 w0 = *(const f4*)(wp + k0);
    f4 w1 = *(const f4*)(wp + k0 + 4);
    f4 w2 = *(const f4*)(wp + k0 + 32);
    f4 w3 = *(const f4*)(wp + k0 + 36);
    bf16x8 a00 = *(const bf16x8*)(ap + k0);
    bf16x8 a01 = *(const bf16x8*)(ap + k0 + 32);
    bf16x8 a10 = *(const bf16x8*)(ap + 16*4096 + k0);
    bf16x8 a11 = *(const bf16x8*)(ap + 16*4096 + k0 + 32);
    bf16x8 a20 = *(const bf16x8*)(ap + 32*4096 + k0);
    bf16x8 a21 = *(const bf16x8*)(ap + 32*4096 + k0 + 32);
    bf16x8 a30 = *(const bf16x8*)(ap + 48*4096 + k0);
    bf16x8 a31 = *(const bf16x8*)(ap + 48*4096 + k0 + 32);
    bf16x8 b0 = pack8(w0,w1), b1 = pack8(w2,w3);
    acc0 = mfma16(a00,b0,acc0); acc1 = mfma16(a10,b0,acc1);
    acc2 = mfma16(a20,b0,acc2); acc3 = mfma16(a30,b0,acc3);
    acc0 = mfma16(a01,b1,acc0); acc1 = mfma16(a11,b1,acc1);
    acc2 = mfma16(a21,b1,acc2); acc3 = mfma16(a31,b1,acc3);
  }
  #pragma unroll
  for(int r=0;r<4;r++){
    red[w][     lq*4+r][lm] = acc0[r];
    red[w][16 + lq*4+r][lm] = acc1[r];
    red[w][32 + lq*4+r][lm] = acc2[r];
    red[w][48 + lq*4+r][lm] = acc3[r];
  }
  __syncthreads();
  int m = tid>>2;
  #pragma unroll
  for(int j=0;j<4;j++){
    int c = (tid&3)*4 + j;
    float v = red[0][m][c]+red[1][m][c]+red[2][m][c]+red[3][m][c];
    gp[(size_t)(half*64+m)*3072 + blockIdx.x*16 + c] = v;
  }
}

// ---- 4: GRU elementwise (sums 2 gi partials + biases) ----
__global__ void k_gru(const float* __restrict__ gp, const float* __restrict__ gh,
                      const float* __restrict__ bih, const float* __restrict__ bhh,
                      const float* __restrict__ h0, float* __restrict__ hid,
                      short* __restrict__ hid_b, short* __restrict__ a2_b){
  int t = blockIdx.x*256 + threadIdx.x;   // 16384
  int b = t>>8, j = (t&255)*4;
  const float* gi0 = gp + (size_t)b*3072 + j;
  const float* gi1 = gp + (size_t)(64+b)*3072 + j;
  const float* ghb = gh + (size_t)b*3072 + j;
  f4 h0v = *(const f4*)(h0 + (size_t)b*1024 + j);
  f4 hres; short4 hb;
  #pragma unroll
  for(int c=0;c<4;c++){
    float r = sigm(gi0[c]      + gi1[c]      + bih[j+c]      + ghb[c]      + bhh[j+c]);
    float z = sigm(gi0[1024+c] + gi1[1024+c] + bih[1024+j+c] + ghb[1024+c] + bhh[1024+j+c]);
    float n = tanhf(gi0[2048+c] + gi1[2048+c] + bih[2048+j+c] + r*(ghb[2048+c] + bhh[2048+j+c]));
    float hv = ((const float*)&h0v)[c];
    float h = (1.0f - z)*n + z*hv;
    ((float*)&hres)[c] = h;
    ((short*)&hb)[c] = f2bf(h);
  }
  *(f4*)(hid + (size_t)b*1024 + j) = hres;
  *(short4*)(hid_b + (size_t)b*1024 + j) = hb;
  *(short4*)(a2_b + (size_t)b*2048 + j) = hb;
}

// ---- 5: blocks 0..511: flash attention chunks; blocks 512..575: W_write gemm ----
__launch_bounds__(256)
__global__ void k_flash(const float* __restrict__ enc, const float* __restrict__ hid,
                        float* __restrict__ part, float* __restrict__ ml,
                        const short* __restrict__ hid_b,
                        const float* __restrict__ Wwrite, const float* __restrict__ bwrite,
                        const float* __restrict__ emog, float* __restrict__ memo){
  __shared__ float red[4][64][20];
  int tid = threadIdx.x;
  int w = tid>>6, l = tid&63;
  if(blockIdx.x < 512){
    int b = blockIdx.x>>3, c = blockIdx.x&7;
    int chunk = c*4 + w;
    const float* hp = hid + (size_t)b*1024 + l*16;
    f4 q0 = *(const f4*)(hp), q1 = *(const f4*)(hp+4);
    f4 q2 = *(const f4*)(hp+8), q3 = *(const f4*)(hp+12);
    f4 cx0={0,0,0,0}, cx1={0,0,0,0}, cx2={0,0,0,0}, cx3={0,0,0,0};
    float mx = -1e30f, ls = 0.0f;
    int s0 = c*32 + w*8;
    for(int si=0; si<8; si++){
      const float* ep = enc + ((size_t)(s0+si)*64 + b)*1024 + l*16;
      f4 e0 = *(const f4*)(ep),   e1 = *(const f4*)(ep+4);
      f4 e2 = *(const f4*)(ep+8), e3 = *(const f4*)(ep+12);
      float d = e0.x*q0.x + e0.y*q0.y + e0.z*q0.z + e0.w*q0.w
              + e1.x*q1.x + e1.y*q1.y + e1.z*q1.z + e1.w*q1.w
              + e2.x*q2.x + e2.y*q2.y + e2.z*q2.z + e2.w*q2.w
              + e3.x*q3.x + e3.y*q3.y + e3.z*q3.z + e3.w*q3.w;
      d = wrsum(d);
      float mn = fmaxf(mx, d);
      float a = expf(mx - mn), p = expf(d - mn);
      ls = ls*a + p;
      cx0.x = cx0.x*a + p*e0.x; cx0.y = cx0.y*a + p*e0.y;
      cx0.z = cx0.z*a + p*e0.z; cx0.w = cx0.w*a + p*e0.w;
      cx1.x = cx1.x*a + p*e1.x; cx1.y = cx1.y*a + p*e1.y;
      cx1.z = cx1.z*a + p*e1.z; cx1.w = cx1.w*a + p*e1.w;
      cx2.x = cx2.x*a + p*e2.x; cx2.y = cx2.y*a + p*e2.y;
      cx2.z = cx2.z*a + p*e2.z; cx2.w = cx2.w*a + p*e2.w;
      cx3.x = cx3.x*a + p*e3.x; cx3.y = cx3.y*a + p*e3.y;
      cx3.z = cx3.z*a + p*e3.z; cx3.w = cx3.w*a + p*e3.w;
      mx = mn;
    }
    float* pp = part + ((size_t)b*32 + chunk)*1024 + l*16;
    *(f4*)(pp)    = cx0; *(f4*)(pp+4)  = cx1;
    *(f4*)(pp+8)  = cx2; *(f4*)(pp+12) = cx3;
    if(l==0){ ml[((size_t)b*32+chunk)*2] = mx; ml[((size_t)b*32+chunk)*2+1] = ls; }
  } else {
    int tile = blockIdx.x - 512;
    int lm = l&15, lq = l>>4;
    int ncol = tile*16 + lm;
    const float* wp = Wwrite + (size_t)ncol*1024 + lq*8;
    const short* ap = hid_b + lm*1024 + lq*8;
    int kbeg = w*256, kend = kbeg + 256;
    f32x4 acc0={0,0,0,0}, acc1={0,0,0,0}, acc2={0,0,0,0}, acc3={0,0,0,0};
    for(int k0=kbeg; k0<kend; k0+=64){
      f4 w0 = *(const f4*)(wp + k0);
      f4 w1 = *(const f4*)(wp + k0 + 4);
      f4 w2 = *(const f4*)(wp + k0 + 32);
      f4 w3 = *(const f4*)(wp + k0 + 36);
      bf16x8 a00 = *(const bf16x8*)(ap + k0);
      bf16x8 a01 = *(const bf16x8*)(ap + k0 + 32);
      bf16x8 a10 = *(const bf16x8*)(ap + 16*1024 + k0);
      bf16x8 a11 = *(const bf16x8*)(ap + 16*1024 + k0 + 32);
      bf16x8 a20 = *(const bf16x8*)(ap + 32*1024 + k0);
      bf16x8 a21 = *(const bf16x8*)(ap + 32*1024 + k0 + 32);
      bf16x8 a30 = *(const bf16x8*)(ap + 48*1024 + k0);
      bf16x8 a31 = *(const bf16x8*)(ap + 48*1024 + k0 + 32);
      bf16x8 b0 = pack8(w0,w1), b1 = pack8(w2,w3);
      acc0 = mfma16(a00,b0,acc0); acc1 = mfma16(a10,b0,acc1);
      acc2 = mfma16(a20,b0,acc2); acc3 = mfma16(a30,b0,acc3);
      acc0 = mfma16(a01,b1,acc0); acc1 = mfma16(a11,b1,acc1);
      acc2 = mfma16(a21,b1,acc2); acc3 = mfma16(a31,b1,acc3);
    }
    #pragma unroll
    for(int r=0;r<4;r++){
      red[w][     lq*4+r][lm] = acc0[r];
      red[w][16 + lq*4+r][lm] = acc1[r];
      red[w][32 + lq*4+r][lm] = acc2[r];
      red[w][48 + lq*4+r][lm] = acc3[r];
    }
    __syncthreads();
    int m = tid>>2;
    #pragma unroll
    for(int j=0;j<4;j++){
      int c = (tid&3)*4 + j;
      float v = red[0][m][c]+red[1][m][c]+red[2][m][c]+red[3][m][c];
      int n = tile*16 + c;
      memo[(size_t)m*1024 + n] = sigm(v + bwrite[n]) * emog[(size_t)m*1024 + n];
    }
  }
}

// ---- 6: merge 32 chunk partials -> context f32 (output) + a2_b[:, 1024:] bf16 ----
__global__ void k_ctxr(const float* __restrict__ part, const float* __restrict__ ml,
                       float* __restrict__ ctxo, short* __restrict__ a2_b){
  int b = blockIdx.x; int t = threadIdx.x;
  __shared__ float sscale[32];
  if(t < 64){
    float mc = (t<32) ? ml[((size_t)b*32+t)*2]   : -1e30f;
    float lc = (t<32) ? ml[((size_t)b*32+t)*2+1] : 0.0f;
    float M = wrmax(mc);
    float L = wrsum(lc * expf(mc - M));
    if(t<32) sscale[t] = expf(mc - M) / L;
  }
  __syncthreads();
  int h = t*4;
  f4 acc = {0,0,0,0};
  for(int c=0;c<32;c++){
    f4 p = *(const f4*)(part + ((size_t)b*32 + c)*1024 + h);
    float s = sscale[c];
    acc.x += s*p.x; acc.y += s*p.y; acc.z += s*p.z; acc.w += s*p.w;
  }
  *(f4*)(ctxo + (size_t)b*1024 + h) = acc;
  *(short4*)(a2_b + (size_t)b*2048 + 1024 + h) =
      make_short4(f2bf(acc.x),f2bf(acc.y),f2bf(acc.z),f2bf(acc.w));
}

// ---- 7: concat_out = tanh(a2 @ W_concat^T + b) -> cc_b bf16 ----
__launch_bounds__(256)
__global__ void k_cc(const short* __restrict__ a2_b, const float* __restrict__ Wc,
                     const float* __restrict__ bc, short* __restrict__ cc_b){
  __shared__ float red[4][64][20];
  int tid = threadIdx.x;
  int w = tid>>6, l = tid&63, lm = l&15, lq = l>>4;
  int ncol = blockIdx.x*16 + lm;
  const float* wp = Wc + (size_t)ncol*2048 + lq*8;
  const short* ap = a2_b + lm*2048 + lq*8;
  int kbeg = w*512, kend = kbeg + 512;
  f32x4 acc0={0,0,0,0}, acc1={0,0,0,0}, acc2={0,0,0,0}, acc3={0,0,0,0};
  for(int k0=kbeg; k0<kend; k0+=64){
    f4 w0 = *(const f4*)(wp + k0);
    f4 w1 = *(const f4*)(wp + k0 + 4);
    f4 w2 = *(const f4*)(wp + k0 + 32);
    f4 w3 = *(const f4*)(wp + k0 + 36);
    bf16x8 a00 = *(const bf16x8*)(ap + k0);
    bf16x8 a01 = *(const bf16x8*)(ap + k0 + 32);
    bf16x8 a10 = *(const bf16x8*)(ap + 16*2048 + k0);
    bf16x8 a11 = *(const bf16x8*)(ap + 16*2048 + k0 + 32);
    bf16x8 a20 = *(const bf16x8*)(ap + 32*2048 + k0);
    bf16x8 a21 = *(const bf16x8*)(ap + 32*2048 + k0 + 32);
    bf16x8 a30 = *(const bf16x8*)(ap + 48*2048 + k0);
    bf16x8 a31 = *(const bf16x8*)(ap + 48*2048 + k0 + 32);
    bf16x8 b0 = pack8(w0,w1), b1 = pack8(w2,w3);
    acc0 = mfma16(a00,b0,acc0); acc1 = mfma16(a10,b0,acc1);
    acc2 = mfma16(a20,b0,acc2); acc3 = mfma16(a30,b0,acc3);
    acc0 = mfma16(a01,b1,acc0); acc1 = mfma16(a11,b1,acc1);
    acc2 = mfma16(a21,b1,acc2); acc3 = mfma16(a31,b1,acc3);
  }
  #pragma unroll
  for(int r=0;r<4;r++){
    red[w][     lq*4+r][lm] = acc0[r];
    red[w][16 + lq*4+r][lm] = acc1[r];
    red[w][32 + lq*4+r][lm] = acc2[r];
    red[w][48 + lq*4+r][lm] = acc3[r];
  }
  __syncthreads();
  int m = tid>>2;
  #pragma unroll
  for(int j=0;j<4;j++){
    int c = (tid&3)*4 + j;
    float v = red[0][m][c]+red[1][m][c]+red[2][m][c]+red[3][m][c];
    int n = blockIdx.x*16 + c;
    cc_b[(size_t)m*1024 + n] = f2bf(tanhf(v + bc[n]));
  }
}

// ---- 8: logits = cc @ W_out^T + b_out. A staged ONCE in LDS (lgkm path);
//         K-loop = pure W-load stream (only vmcnt user) + MFMA. Fused stats. ----
__launch_bounds__(256)
__global__ void k_out(const short* __restrict__ A, const float* __restrict__ Wm,
                      const float* __restrict__ bias, const float* __restrict__ wal,
                      const int* __restrict__ mem,
                      float* __restrict__ outf, float* __restrict__ pstat){
  __shared__ short As[64][1032];     // 129 KB, +8 shorts pad per row (bank spread)
  __shared__ float sst[4][64][6];
  int tid = threadIdx.x;
  int w = tid>>6, l = tid&63;
  int lm = l&15, lq = l>>4;

  // one-time A stage (L2-hot 128 KB): 4 threads/row, 512 B each
  {
    int row = tid>>2, seg = tid&3;
    const short* src = A + (size_t)row*1024 + seg*256;
    short* dst = &As[row][seg*256];
    #pragma unroll
    for(int i=0;i<32;i++)
      *(f4*)(dst + i*8) = *(const f4*)(src + i*8);
  }
  __syncthreads();

  int n0 = blockIdx.x*64;
  int ncol = n0 + w*16 + lm;
  int nrow = ncol < V ? ncol : V-1;
  const float* wp = Wm + (size_t)nrow*1024 + lq*8;
  f32x4 acc0={0,0,0,0}, acc1={0,0,0,0}, acc2={0,0,0,0}, acc3={0,0,0,0};

  #pragma unroll
  for(int k0=0; k0<1024; k0+=64){
    f4 w0 = *(const f4*)(wp + k0);
    f4 w1 = *(const f4*)(wp + k0 + 4);
    f4 w2 = *(const f4*)(wp + k0 + 32);
    f4 w3 = *(const f4*)(wp + k0 + 36);
    bf16x8 b0 = pack8(w0,w1), b1 = pack8(w2,w3);
    int ka = lq*8 + k0;
    bf16x8 a00 = *(const bf16x8*)(&As[lm   ][ka]);
    bf16x8 a01 = *(const bf16x8*)(&As[lm   ][ka+32]);
    bf16x8 a10 = *(const bf16x8*)(&As[16+lm][ka]);
    bf16x8 a11 = *(const bf16x8*)(&As[16+lm][ka+32]);
    bf16x8 a20 = *(const bf16x8*)(&As[32+lm][ka]);
    bf16x8 a21 = *(const bf16x8*)(&As[32+lm][ka+32]);
    bf16x8 a30 = *(const bf16x8*)(&As[48+lm][ka]);
    bf16x8 a31 = *(const bf16x8*)(&As[48+lm][ka+32]);
    acc0 = mfma16(a00,b0,acc0); acc1 = mfma16(a10,b0,acc1);
    acc2 = mfma16(a20,b0,acc2); acc3 = mfma16(a30,b0,acc3);
    acc0 = mfma16(a01,b1,acc0); acc1 = mfma16(a11,b1,acc1);
    acc2 = mfma16(a21,b1,acc2); acc3 = mfma16(a31,b1,acc3);
  }

  // epilogue: bias + store + fused row stats (16-lane butterfly per row)
  float bv=0.0f, wv=0.0f; int mv=-1;
  if(ncol < V){ bv = bias[ncol]; wv = wal[ncol]; mv = mem[ncol]; }
  #pragma unroll
  for(int qi=0; qi<4; qi++){
    #pragma unroll
    for(int r=0;r<4;r++){
      float v;
      if(qi==0) v = acc0[r]+bv; else if(qi==1) v = acc1[r]+bv;
      else if(qi==2) v = acc2[r]+bv; else v = acc3[r]+bv;
      int row = lq*4 + r + 16*qi;
      if(ncol < V) outf[(size_t)row*V + ncol] = v;
      float dd = v*wv;
      float em = (mv==1) ? v : -1e30f;
      float gm = (mv==0) ? v : -1e30f;
      #pragma unroll
      for(int o=1;o<16;o<<=1){
        dd += __shfl_xor(dd,o);
        em = fmaxf(em, __shfl_xor(em,o));
        gm = fmaxf(gm, __shfl_xor(gm,o));
      }
      float pe = (mv==1) ? expf(v - em) : 0.0f;
      float pg = (mv==0) ? expf(v - gm) : 0.0f;
      #pragma unroll
      for(int o=1;o<16;o<<=1){
        pe += __shfl_xor(pe,o);
        pg += __shfl_xor(pg,o);
      }
      if(lm==0){
        sst[w][row][0]=dd; sst[w][row][1]=em; sst[w][row][2]=pe;
        sst[w][row][3]=gm; sst[w][row][4]=pg;
      }
    }
  }
  __syncthreads();
  if(tid < 64){
    float dd=0.0f, me=-1e30f, se=0.0f, mg=-1e30f, sg=0.0f;
    #pragma unroll
    for(int g=0; g<4; g++){
      dd += sst[g][tid][0];
      float m2=sst[g][tid][1], s2=sst[g][tid][2];
      float nm=fmaxf(me,m2); se = se*expf(me-nm) + s2*expf(m2-nm); me = nm;
      m2=sst[g][tid][3]; s2=sst[g][tid][4];
      nm=fmaxf(mg,m2); sg = sg*expf(mg-nm) + s2*expf(m2-nm); mg = nm;
    }
    float* pp = pstat + ((size_t)tid*NBLK + blockIdx.x)*6;
    pp[0]=dd; pp[1]=me; pp[2]=se; pp[3]=mg; pp[4]=sg;
  }
}

// ---- 9: merge per-block stats partials -> stats[b][8] ----
__global__ void k_merge(const float* __restrict__ pstat, float* __restrict__ stats){
  int b = blockIdx.x, t = threadIdx.x;
  float dd=0.0f, me=-1e30f, se=0.0f, mg=-1e30f, sg=0.0f;
  for(int i=t; i<NBLK; i+=256){
    const float* pp = pstat + ((size_t)b*NBLK + i)*6;
    dd += pp[0];
    float m2=pp[1], s2=pp[2];
    float nm=fmaxf(me,m2); se = se*expf(me-nm) + s2*expf(m2-nm); me = nm;
    m2=pp[3]; s2=pp[4];
    nm=fmaxf(mg,m2); sg = sg*expf(mg-nm) + s2*expf(m2-nm); mg = nm;
  }
  #pragma unroll
  for(int o=32;o;o>>=1){
    dd += __shfl_xor(dd,o);
    float m2=__shfl_xor(me,o), s2=__shfl_xor(se,o);
    float nm=fmaxf(me,m2); se = se*expf(me-nm) + s2*expf(m2-nm); me = nm;
    m2=__shfl_xor(mg,o); s2=__shfl_xor(sg,o);
    nm=fmaxf(mg,m2); sg = sg*expf(mg-nm) + s2*expf(m2-nm); mg = nm;
  }
  __shared__ float sm[4][5];
  int wv = t>>6;
  if((t&63)==0){ sm[wv][0]=dd; sm[wv][1]=me; sm[wv][2]=se; sm[wv][3]=mg; sm[wv][4]=sg; }
  __syncthreads();
  if(t==0){
    float D=0, M=-1e30f, S=0, M2=-1e30f, S2=0;
    for(int i=0;i<4;i++){
      D += sm[i][0];
      float m = fmaxf(M, sm[i][1]); S  = S*expf(M-m)  + sm[i][2]*expf(sm[i][1]-m);  M = m;
      float n = fmaxf(M2,sm[i][3]); S2 = S2*expf(M2-n)+ sm[i][4]*expf(sm[i][3]-n); M2 = n;
    }
    stats[b*8+0]=D; stats[b*8+1]=M; stats[b*8+2]=M2; stats[b*8+3]=S; stats[b*8+4]=S2;
  }
}

// ---- 10: dual gated softmax in-place ----
__global__ void k_final(float* __restrict__ logits, const int* __restrict__ mem,
                        const float* __restrict__ stats, const float* __restrict__ balpha){
  int v = blockIdx.x*256 + threadIdx.x;
  int b = blockIdx.y;
  if(v >= V) return;
  float dot = stats[b*8+0], me = stats[b*8+1], mg = stats[b*8+2];
  float se = stats[b*8+3],  sg = stats[b*8+4];
  float g = sigm(dot + balpha[0]);
  float l = logits[(size_t)b*V + v];
  float o = (mem[v]==1) ? (expf(l-me)/se * g) : (expf(l-mg)/sg * (1.0f-g));
  logits[(size_t)b*V + v] = o;
}

extern "C" void kernel_launch(void* const* d_in, const int* in_sizes, int n_in,
                              void* d_out, int out_size, void* d_ws, size_t ws_size,
                              hipStream_t stream){
  const int*   istep   = (const int*)d_in[0];
  const int*   iemo    = (const int*)d_in[1];
  const float* lasth   = (const float*)d_in[2];
  const float* ictx    = (const float*)d_in[3];
  const float* enc     = (const float*)d_in[4];
  const int*   emem    = (const int*)d_in[5];
  const float* emb     = (const float*)d_in[6];
  const float* eemb    = (const float*)d_in[7];
  const float* W_read  = (const float*)d_in[8];
  const float* b_read  = (const float*)d_in[9];
  const float* W_write = (const float*)d_in[10];
  const float* b_write = (const float*)d_in[11];
  const float* W_ih    = (const float*)d_in[12];
  const float* W_hh    = (const float*)d_in[13];
  const float* b_ih    = (const float*)d_in[14];
  const float* b_hh    = (const float*)d_in[15];
  const float* W_concat= (const float*)d_in[16];
  const float* b_concat= (const float*)d_in[17];
  const float* W_out   = (const float*)d_in[18];
  const float* b_out   = (const float*)d_in[19];
  const float* W_alpha = (const float*)d_in[20];
  const float* b_alpha = (const float*)d_in[21];

  short* X_b  = (short*)d_ws;                           // 64x4096 bf16
  float* emog = (float*)((char*)d_ws + 524288);         // 64x1024
  float* gp   = emog + 65536;                           // 2x64x3072 (gi partials)
  float* gh   = gp + 393216;                            // 64x3072
  float* part = gh + 196608;                            // 64x32x1024
  float* ml   = part + 2097152;                         // 64x32x2
  float* stats= ml + 4096;                              // 512
  float* pstat= stats + 512;                            // 64x786x6
  short* hid_b= (short*)(pstat + 64*NBLK*6);            // 64x1024 bf16
  short* a2_b = hid_b + 65536;                          // 64x2048 bf16
  short* cc_b = a2_b + 131072;                          // 64x1024 bf16

  float* out0 = (float*)d_out;          // [64][V]
  float* hid  = out0 + (size_t)B*V;     // [64][1024] (output: hidden)
  float* memo = hid + 65536;            // [64][1024] (output: new_M_emo)
  float* ctxo = memo + 65536;           // [64][1024] (output: context)

  k_build<<<64,256,0,stream>>>(istep, lasth, ictx, emb, X_b);
  k_pre  <<<256,256,0,stream>>>(iemo, X_b, eemb, W_read, b_read, W_hh, emog, X_b, gh);
  k_gi   <<<dim3(192,2),256,0,stream>>>(X_b, W_ih, gp);
  k_gru  <<<64,256,0,stream>>>(gp, gh, b_ih, b_hh, lasth, hid, hid_b, a2_b);
  k_flash<<<576,256,0,stream>>>(enc, hid, part, ml, hid_b, W_write, b_write, emog, memo);
  k_ctxr <<<64,256,0,stream>>>(part, ml, ctxo, a2_b);
  k_cc   <<<64,256,0,stream>>>(a2_b, W_concat, b_concat, cc_b);
  k_out  <<<NBLK,256,0,stream>>>(cc_b, W_out, b_out, W_alpha, emem, out0, pstat);
  k_merge<<<64,256,0,stream>>>(pstat, stats);
  k_final<<<dim3(197,64),256,0,stream>>>(out0, emem, stats, b_alpha);
}

// Round 12
// 186.954 us; speedup vs baseline: 1.6198x; 1.2783x over previous
//
#include <hip/hip_runtime.h>
#include <hip/hip_bf16.h>
#include <math.h>

#define B 64
#define H 1024
#define SEQ 256
#define V 50257
#define NBLK 786   // ceil(V/64)

typedef float4 f4;
typedef __attribute__((ext_vector_type(4))) float f32x4;
typedef __attribute__((ext_vector_type(8))) short bf16x8;

__device__ inline float sigm(float x){ return 1.0f/(1.0f+expf(-x)); }
__device__ inline short f2bf(float x){
  __hip_bfloat16 h = __float2bfloat16(x);
  union { __hip_bfloat16 h; short s; } u; u.h = h; return u.s;
}
__device__ inline short2 cvt2(float x, float y){
  __hip_bfloat162 h = __float22bfloat162_rn(float2{x, y});
  union { __hip_bfloat162 h; short2 s; } u; u.h = h; return u.s;
}
__device__ inline bf16x8 pack8(f4 lo, f4 hi){
  union { bf16x8 v; short2 s[4]; } u;
  u.s[0]=cvt2(lo.x,lo.y); u.s[1]=cvt2(lo.z,lo.w);
  u.s[2]=cvt2(hi.x,hi.y); u.s[3]=cvt2(hi.z,hi.w);
  return u.v;
}
__device__ inline float wrsum(float v){
  #pragma unroll
  for(int o=32;o;o>>=1) v += __shfl_xor(v,o);
  return v;
}
__device__ inline float wrmax(float v){
  #pragma unroll
  for(int o=32;o;o>>=1) v = fmaxf(v,__shfl_xor(v,o));
  return v;
}
__device__ inline f32x4 mfma16(bf16x8 a, bf16x8 b, f32x4 c){
  return __builtin_amdgcn_mfma_f32_16x16x32_bf16(a,b,c,0,0,0);
}
// async global->LDS, 16B per lane; lds base must be wave-uniform (HW: base + lane*16)
__device__ inline void gll16(const void* g, void* l){
  __builtin_amdgcn_global_load_lds((const __attribute__((address_space(1))) void*)g,
                                   (__attribute__((address_space(3))) void*)l, 16, 0, 0);
}

// ---- 1: build X_b[:, :3072] = bf16[emb(iw) | lasth | ictx] ----
__global__ void k_build(const int* __restrict__ istep,
                        const float* __restrict__ lasth, const float* __restrict__ ictx,
                        const float* __restrict__ emb, short* __restrict__ X_b){
  int b = blockIdx.x; int h = threadIdx.x*4;
  int iw = istep[b];
  f4 lw = *(const f4*)(emb  + (size_t)iw*H + h);
  f4 hs = *(const f4*)(lasth + (size_t)b*H + h);
  f4 cv = *(const f4*)(ictx + (size_t)b*H + h);
  short* xb = X_b + (size_t)b*4096;
  *(short4*)(xb +        h) = make_short4(f2bf(lw.x),f2bf(lw.y),f2bf(lw.z),f2bf(lw.w));
  *(short4*)(xb + 1024 + h) = make_short4(f2bf(hs.x),f2bf(hs.y),f2bf(hs.z),f2bf(hs.w));
  *(short4*)(xb + 2048 + h) = make_short4(f2bf(cv.x),f2bf(cv.y),f2bf(cv.z),f2bf(cv.w));
}

// ---- 2: blocks 0..63: W_read gemm + sigmoid*eemb -> emog f32 + X_b[:,3072:] bf16
//         blocks 64..255: W_hh gemm (192 tiles) -> gh raw f32 ----
__launch_bounds__(256)
__global__ void k_pre(const int* __restrict__ iemo, const short* __restrict__ X_b,
                      const float* __restrict__ eemb,
                      const float* __restrict__ Wread, const float* __restrict__ bread,
                      const float* __restrict__ Whh,
                      float* __restrict__ emog, short* __restrict__ X_b_w,
                      float* __restrict__ gh){
  __shared__ float red[4][64][20];
  int tid = threadIdx.x;
  int w = tid>>6, l = tid&63, lm = l&15, lq = l>>4;
  f32x4 acc0={0,0,0,0}, acc1={0,0,0,0}, acc2={0,0,0,0}, acc3={0,0,0,0};
  int readmode = (blockIdx.x < 64);
  int tile = readmode ? blockIdx.x : (blockIdx.x - 64);
  int ncol = tile*16 + lm;
  const float* wp = readmode ? (Wread + (size_t)ncol*3072 + lq*8)
                             : (Whh   + (size_t)ncol*1024 + lq*8);
  const short* ap = readmode ? (X_b + lm*4096 + lq*8)
                             : (X_b + 1024 + lm*4096 + lq*8);
  int kbeg = readmode ? w*768 : w*256;
  int kend = readmode ? (kbeg + 768) : (kbeg + 256);
  for(int k0=kbeg; k0<kend; k0+=64){
    f4 w0 = *(const f4*)(wp + k0);
    f4 w1 = *(const f4*)(wp + k0 + 4);
    f4 w2 = *(const f4*)(wp + k0 + 32);
    f4 w3 = *(const f4*)(wp + k0 + 36);
    bf16x8 a00 = *(const bf16x8*)(ap + k0);
    bf16x8 a01 = *(const bf16x8*)(ap + k0 + 32);
    bf16x8 a10 = *(const bf16x8*)(ap + 16*4096 + k0);
    bf16x8 a11 = *(const bf16x8*)(ap + 16*4096 + k0 + 32);
    bf16x8 a20 = *(const bf16x8*)(ap + 32*4096 + k0);
    bf16x8 a21 = *(const bf16x8*)(ap + 32*4096 + k0 + 32);
    bf16x8 a30 = *(const bf16x8*)(ap + 48*4096 + k0);
    bf16x8 a31 = *(const bf16x8*)(ap + 48*4096 + k0 + 32);
    bf16x8 b0 = pack8(w0,w1), b1 = pack8(w2,w3);
    acc0 = mfma16(a00,b0,acc0); acc1 = mfma16(a10,b0,acc1);
    acc2 = mfma16(a20,b0,acc2); acc3 = mfma16(a30,b0,acc3);
    acc0 = mfma16(a01,b1,acc0); acc1 = mfma16(a11,b1,acc1);
    acc2 = mfma16(a21,b1,acc2); acc3 = mfma16(a31,b1,acc3);
  }
  #pragma unroll
  for(int r=0;r<4;r++){
    red[w][     lq*4+r][lm] = acc0[r];
    red[w][16 + lq*4+r][lm] = acc1[r];
    red[w][32 + lq*4+r][lm] = acc2[r];
    red[w][48 + lq*4+r][lm] = acc3[r];
  }
  __syncthreads();
  int m = tid>>2;
  if(readmode){
    int ie = iemo[m];
    #pragma unroll
    for(int j=0;j<4;j++){
      int c = (tid&3)*4 + j;
      float v = red[0][m][c]+red[1][m][c]+red[2][m][c]+red[3][m][c];
      int n = tile*16 + c;
      float s = sigm(v + bread[n]);
      float eg = s * eemb[(size_t)ie*1024 + n];
      emog[(size_t)m*1024 + n] = eg;
      X_b_w[(size_t)m*4096 + 3072 + n] = f2bf(eg);
    }
  } else {
    #pragma unroll
    for(int j=0;j<4;j++){
      int c = (tid&3)*4 + j;
      float v = red[0][m][c]+red[1][m][c]+red[2][m][c]+red[3][m][c];
      gh[(size_t)m*3072 + tile*16 + c] = v;
    }
  }
}

// ---- 3: gi partials = X @ W_ih^T, 2-way K-split (grid (192,2)) ----
__launch_bounds__(256)
__global__ void k_gi(const short* __restrict__ X_b, const float* __restrict__ Wih,
                     float* __restrict__ gp){
  __shared__ float red[4][64][20];
  int tid = threadIdx.x;
  int w = tid>>6, l = tid&63, lm = l&15, lq = l>>4;
  int half = blockIdx.y;
  int ncol = blockIdx.x*16 + lm;
  const float* wp = Wih + (size_t)ncol*4096 + lq*8;
  const short* ap = X_b + lm*4096 + lq*8;
  int kbeg = half*2048 + w*512, kend = kbeg + 512;
  f32x4 acc0={0,0,0,0}, acc1={0,0,0,0}, acc2={0,0,0,0}, acc3={0,0,0,0};
  for(int k0=kbeg; k0<kend; k0+=64){
    f4 w0 = *(const f4*)(wp + k0);
    f4 w1 = *(const f4*)(wp + k0 + 4);
    f4 w2 = *(const f4*)(wp + k0 + 32);
    f4 w3 = *(const f4*)(wp + k0 + 36);
    bf16x8 a00 = *(const bf16x8*)(ap + k0);
    bf16x8 a01 = *(const bf16x8*)(ap + k0 + 32);
    bf16x8 a10 = *(const bf16x8*)(ap + 16*4096 + k0);
    bf16x8 a11 = *(const bf16x8*)(ap + 16*4096 + k0 + 32);
    bf16x8 a20 = *(const bf16x8*)(ap + 32*4096 + k0);
    bf16x8 a21 = *(const bf16x8*)(ap + 32*4096 + k0 + 32);
    bf16x8 a30 = *(const bf16x8*)(ap + 48*4096 + k0);
    bf16x8 a31 = *(const bf16x8*)(ap + 48*4096 + k0 + 32);
    bf16x8 b0 = pack8(w0,w1), b1 = pack8(w2,w3);
    acc0 = mfma16(a00,b0,acc0); acc1 = mfma16(a10,b0,acc1);
    acc2 = mfma16(a20,b0,acc2); acc3 = mfma16(a30,b0,acc3);
    acc0 = mfma16(a01,b1,acc0); acc1 = mfma16(a11,b1,acc1);
    acc2 = mfma16(a21,b1,acc2); acc3 = mfma16(a31,b1,acc3);
  }
  #pragma unroll
  for(int r=0;r<4;r++){
    red[w][     lq*4+r][lm] = acc0[r];
    red[w][16 + lq*4+r][lm] = acc1[r];
    red[w][32 + lq*4+r][lm] = acc2[r];
    red[w][48 + lq*4+r][lm] = acc3[r];
  }
  __syncthreads();
  int m = tid>>2;
  #pragma unroll
  for(int j=0;j<4;j++){
    int c = (tid&3)*4 + j;
    float v = red[0][m][c]+red[1][m][c]+red[2][m][c]+red[3][m][c];
    gp[(size_t)(half*64+m)*3072 + blockIdx.x*16 + c] = v;
  }
}

// ---- 4: GRU elementwise (sums 2 gi partials + biases) ----
__global__ void k_gru(const float* __restrict__ gp, const float* __restrict__ gh,
                      const float* __restrict__ bih, const float* __restrict__ bhh,
                      const float* __restrict__ h0, float* __restrict__ hid,
                      short* __restrict__ hid_b, short* __restrict__ a2_b){
  int t = blockIdx.x*256 + threadIdx.x;   // 16384
  int b = t>>8, j = (t&255)*4;
  const float* gi0 = gp + (size_t)b*3072 + j;
  const float* gi1 = gp + (size_t)(64+b)*3072 + j;
  const float* ghb = gh + (size_t)b*3072 + j;
  f4 h0v = *(const f4*)(h0 + (size_t)b*1024 + j);
  f4 hres; short4 hb;
  #pragma unroll
  for(int c=0;c<4;c++){
    float r = sigm(gi0[c]      + gi1[c]      + bih[j+c]      + ghb[c]      + bhh[j+c]);
    float z = sigm(gi0[1024+c] + gi1[1024+c] + bih[1024+j+c] + ghb[1024+c] + bhh[1024+j+c]);
    float n = tanhf(gi0[2048+c] + gi1[2048+c] + bih[2048+j+c] + r*(ghb[2048+c] + bhh[2048+j+c]));
    float hv = ((const float*)&h0v)[c];
    float h = (1.0f - z)*n + z*hv;
    ((float*)&hres)[c] = h;
    ((short*)&hb)[c] = f2bf(h);
  }
  *(f4*)(hid + (size_t)b*1024 + j) = hres;
  *(short4*)(hid_b + (size_t)b*1024 + j) = hb;
  *(short4*)(a2_b + (size_t)b*2048 + j) = hb;
}

// ---- 5: blocks 0..511: flash attention chunks; blocks 512..575: W_write gemm ----
__launch_bounds__(256)
__global__ void k_flash(const float* __restrict__ enc, const float* __restrict__ hid,
                        float* __restrict__ part, float* __restrict__ ml,
                        const short* __restrict__ hid_b,
                        const float* __restrict__ Wwrite, const float* __restrict__ bwrite,
                        const float* __restrict__ emog, float* __restrict__ memo){
  __shared__ float red[4][64][20];
  int tid = threadIdx.x;
  int w = tid>>6, l = tid&63;
  if(blockIdx.x < 512){
    int b = blockIdx.x>>3, c = blockIdx.x&7;
    int chunk = c*4 + w;
    const float* hp = hid + (size_t)b*1024 + l*16;
    f4 q0 = *(const f4*)(hp), q1 = *(const f4*)(hp+4);
    f4 q2 = *(const f4*)(hp+8), q3 = *(const f4*)(hp+12);
    f4 cx0={0,0,0,0}, cx1={0,0,0,0}, cx2={0,0,0,0}, cx3={0,0,0,0};
    float mx = -1e30f, ls = 0.0f;
    int s0 = c*32 + w*8;
    for(int si=0; si<8; si++){
      const float* ep = enc + ((size_t)(s0+si)*64 + b)*1024 + l*16;
      f4 e0 = *(const f4*)(ep),   e1 = *(const f4*)(ep+4);
      f4 e2 = *(const f4*)(ep+8), e3 = *(const f4*)(ep+12);
      float d = e0.x*q0.x + e0.y*q0.y + e0.z*q0.z + e0.w*q0.w
              + e1.x*q1.x + e1.y*q1.y + e1.z*q1.z + e1.w*q1.w
              + e2.x*q2.x + e2.y*q2.y + e2.z*q2.z + e2.w*q2.w
              + e3.x*q3.x + e3.y*q3.y + e3.z*q3.z + e3.w*q3.w;
      d = wrsum(d);
      float mn = fmaxf(mx, d);
      float a = expf(mx - mn), p = expf(d - mn);
      ls = ls*a + p;
      cx0.x = cx0.x*a + p*e0.x; cx0.y = cx0.y*a + p*e0.y;
      cx0.z = cx0.z*a + p*e0.z; cx0.w = cx0.w*a + p*e0.w;
      cx1.x = cx1.x*a + p*e1.x; cx1.y = cx1.y*a + p*e1.y;
      cx1.z = cx1.z*a + p*e1.z; cx1.w = cx1.w*a + p*e1.w;
      cx2.x = cx2.x*a + p*e2.x; cx2.y = cx2.y*a + p*e2.y;
      cx2.z = cx2.z*a + p*e2.z; cx2.w = cx2.w*a + p*e2.w;
      cx3.x = cx3.x*a + p*e3.x; cx3.y = cx3.y*a + p*e3.y;
      cx3.z = cx3.z*a + p*e3.z; cx3.w = cx3.w*a + p*e3.w;
      mx = mn;
    }
    float* pp = part + ((size_t)b*32 + chunk)*1024 + l*16;
    *(f4*)(pp)    = cx0; *(f4*)(pp+4)  = cx1;
    *(f4*)(pp+8)  = cx2; *(f4*)(pp+12) = cx3;
    if(l==0){ ml[((size_t)b*32+chunk)*2] = mx; ml[((size_t)b*32+chunk)*2+1] = ls; }
  } else {
    int tile = blockIdx.x - 512;
    int lm = l&15, lq = l>>4;
    int ncol = tile*16 + lm;
    const float* wp = Wwrite + (size_t)ncol*1024 + lq*8;
    const short* ap = hid_b + lm*1024 + lq*8;
    int kbeg = w*256, kend = kbeg + 256;
    f32x4 acc0={0,0,0,0}, acc1={0,0,0,0}, acc2={0,0,0,0}, acc3={0,0,0,0};
    for(int k0=kbeg; k0<kend; k0+=64){
      f4 w0 = *(const f4*)(wp + k0);
      f4 w1 = *(const f4*)(wp + k0 + 4);
      f4 w2 = *(const f4*)(wp + k0 + 32);
      f4 w3 = *(const f4*)(wp + k0 + 36);
      bf16x8 a00 = *(const bf16x8*)(ap + k0);
      bf16x8 a01 = *(const bf16x8*)(ap + k0 + 32);
      bf16x8 a10 = *(const bf16x8*)(ap + 16*1024 + k0);
      bf16x8 a11 = *(const bf16x8*)(ap + 16*1024 + k0 + 32);
      bf16x8 a20 = *(const bf16x8*)(ap + 32*1024 + k0);
      bf16x8 a21 = *(const bf16x8*)(ap + 32*1024 + k0 + 32);
      bf16x8 a30 = *(const bf16x8*)(ap + 48*1024 + k0);
      bf16x8 a31 = *(const bf16x8*)(ap + 48*1024 + k0 + 32);
      bf16x8 b0 = pack8(w0,w1), b1 = pack8(w2,w3);
      acc0 = mfma16(a00,b0,acc0); acc1 = mfma16(a10,b0,acc1);
      acc2 = mfma16(a20,b0,acc2); acc3 = mfma16(a30,b0,acc3);
      acc0 = mfma16(a01,b1,acc0); acc1 = mfma16(a11,b1,acc1);
      acc2 = mfma16(a21,b1,acc2); acc3 = mfma16(a31,b1,acc3);
    }
    #pragma unroll
    for(int r=0;r<4;r++){
      red[w][     lq*4+r][lm] = acc0[r];
      red[w][16 + lq*4+r][lm] = acc1[r];
      red[w][32 + lq*4+r][lm] = acc2[r];
      red[w][48 + lq*4+r][lm] = acc3[r];
    }
    __syncthreads();
    int m = tid>>2;
    #pragma unroll
    for(int j=0;j<4;j++){
      int c = (tid&3)*4 + j;
      float v = red[0][m][c]+red[1][m][c]+red[2][m][c]+red[3][m][c];
      int n = tile*16 + c;
      memo[(size_t)m*1024 + n] = sigm(v + bwrite[n]) * emog[(size_t)m*1024 + n];
    }
  }
}

// ---- 6: merge 32 chunk partials -> context f32 (output) + a2_b[:, 1024:] bf16 ----
__global__ void k_ctxr(const float* __restrict__ part, const float* __restrict__ ml,
                       float* __restrict__ ctxo, short* __restrict__ a2_b){
  int b = blockIdx.x; int t = threadIdx.x;
  __shared__ float sscale[32];
  if(t < 64){
    float mc = (t<32) ? ml[((size_t)b*32+t)*2]   : -1e30f;
    float lc = (t<32) ? ml[((size_t)b*32+t)*2+1] : 0.0f;
    float M = wrmax(mc);
    float L = wrsum(lc * expf(mc - M));
    if(t<32) sscale[t] = expf(mc - M) / L;
  }
  __syncthreads();
  int h = t*4;
  f4 acc = {0,0,0,0};
  for(int c=0;c<32;c++){
    f4 p = *(const f4*)(part + ((size_t)b*32 + c)*1024 + h);
    float s = sscale[c];
    acc.x += s*p.x; acc.y += s*p.y; acc.z += s*p.z; acc.w += s*p.w;
  }
  *(f4*)(ctxo + (size_t)b*1024 + h) = acc;
  *(short4*)(a2_b + (size_t)b*2048 + 1024 + h) =
      make_short4(f2bf(acc.x),f2bf(acc.y),f2bf(acc.z),f2bf(acc.w));
}

// ---- 7: concat_out = tanh(a2 @ W_concat^T + b) -> cc_b bf16 ----
__launch_bounds__(256)
__global__ void k_cc(const short* __restrict__ a2_b, const float* __restrict__ Wc,
                     const float* __restrict__ bc, short* __restrict__ cc_b){
  __shared__ float red[4][64][20];
  int tid = threadIdx.x;
  int w = tid>>6, l = tid&63, lm = l&15, lq = l>>4;
  int ncol = blockIdx.x*16 + lm;
  const float* wp = Wc + (size_t)ncol*2048 + lq*8;
  const short* ap = a2_b + lm*2048 + lq*8;
  int kbeg = w*512, kend = kbeg + 512;
  f32x4 acc0={0,0,0,0}, acc1={0,0,0,0}, acc2={0,0,0,0}, acc3={0,0,0,0};
  for(int k0=kbeg; k0<kend; k0+=64){
    f4 w0 = *(const f4*)(wp + k0);
    f4 w1 = *(const f4*)(wp + k0 + 4);
    f4 w2 = *(const f4*)(wp + k0 + 32);
    f4 w3 = *(const f4*)(wp + k0 + 36);
    bf16x8 a00 = *(const bf16x8*)(ap + k0);
    bf16x8 a01 = *(const bf16x8*)(ap + k0 + 32);
    bf16x8 a10 = *(const bf16x8*)(ap + 16*2048 + k0);
    bf16x8 a11 = *(const bf16x8*)(ap + 16*2048 + k0 + 32);
    bf16x8 a20 = *(const bf16x8*)(ap + 32*2048 + k0);
    bf16x8 a21 = *(const bf16x8*)(ap + 32*2048 + k0 + 32);
    bf16x8 a30 = *(const bf16x8*)(ap + 48*2048 + k0);
    bf16x8 a31 = *(const bf16x8*)(ap + 48*2048 + k0 + 32);
    bf16x8 b0 = pack8(w0,w1), b1 = pack8(w2,w3);
    acc0 = mfma16(a00,b0,acc0); acc1 = mfma16(a10,b0,acc1);
    acc2 = mfma16(a20,b0,acc2); acc3 = mfma16(a30,b0,acc3);
    acc0 = mfma16(a01,b1,acc0); acc1 = mfma16(a11,b1,acc1);
    acc2 = mfma16(a21,b1,acc2); acc3 = mfma16(a31,b1,acc3);
  }
  #pragma unroll
  for(int r=0;r<4;r++){
    red[w][     lq*4+r][lm] = acc0[r];
    red[w][16 + lq*4+r][lm] = acc1[r];
    red[w][32 + lq*4+r][lm] = acc2[r];
    red[w][48 + lq*4+r][lm] = acc3[r];
  }
  __syncthreads();
  int m = tid>>2;
  #pragma unroll
  for(int j=0;j<4;j++){
    int c = (tid&3)*4 + j;
    float v = red[0][m][c]+red[1][m][c]+red[2][m][c]+red[3][m][c];
    int n = blockIdx.x*16 + c;
    cc_b[(size_t)m*1024 + n] = f2bf(tanhf(v + bc[n]));
  }
}

// ---- 8: logits = cc @ W_out^T + b_out. m97-style: global_load_lds staging
//         (linear LDS dest, XOR-swizzled global source + swizzled ds_read),
//         double-buffered K-step 64, fused row stats ----
__launch_bounds__(256)
__global__ void k_out(const short* __restrict__ A, const float* __restrict__ Wm,
                      const float* __restrict__ bias, const float* __restrict__ wal,
                      const int* __restrict__ mem,
                      float* __restrict__ outf, float* __restrict__ pstat){
  __shared__ float Wt[2][64][64];   // 32 KB: W tile, rows = out cols, 16 segs(16B)/row
  __shared__ short At[2][64][64];   // 16 KB: A tile, 8 segs(16B)/row
  __shared__ float sst[4][64][6];
  int tid = threadIdx.x;
  int w = tid>>6, l = tid&63;
  int lm = l&15, lq = l>>4;
  int n0 = blockIdx.x*64;

  // per-lane staging constants
  //  W: 4 calls/wave; call i: lane l -> tile row Rw = w*16+i*4+(l>>4), seg l&15
  int wRl = l>>4, wSeg = l&15;
  //  A: 2 calls/wave; call j: lane l -> tile row Ra = w*16+j*8+(l>>3), seg l&7
  int aRl = l>>3, aSeg = l&7;

  f32x4 acc0={0,0,0,0}, acc1={0,0,0,0}, acc2={0,0,0,0}, acc3={0,0,0,0};

  // ---- stage step 0 into buf 0 ----
  {
    int k0 = 0;
    #pragma unroll
    for(int i=0;i<4;i++){
      int R = w*16 + i*4 + wRl;
      int gr = n0 + R; if(gr > V-1) gr = V-1;
      const float* gp = Wm + (size_t)gr*1024 + k0 + (size_t)(wSeg ^ (R&7))*4;
      gll16(gp, &Wt[0][w*16 + i*4][0]);
    }
    #pragma unroll
    for(int j=0;j<2;j++){
      int R = w*16 + j*8 + aRl;
      const short* gp = A + (size_t)R*1024 + k0 + (size_t)(aSeg ^ (R&7))*8;
      gll16(gp, &At[0][w*16 + j*8][0]);
    }
  }
  __syncthreads();

  int buf = 0;
  for(int step=0; step<16; step++){
    if(step < 15){
      int k0 = (step+1)*64;
      #pragma unroll
      for(int i=0;i<4;i++){
        int R = w*16 + i*4 + wRl;
        int gr = n0 + R; if(gr > V-1) gr = V-1;
        const float* gp = Wm + (size_t)gr*1024 + k0 + (size_t)(wSeg ^ (R&7))*4;
        gll16(gp, &Wt[buf^1][w*16 + i*4][0]);
      }
      #pragma unroll
      for(int j=0;j<2;j++){
        int R = w*16 + j*8 + aRl;
        const short* gp = A + (size_t)R*1024 + k0 + (size_t)(aSeg ^ (R&7))*8;
        gll16(gp, &At[buf^1][w*16 + j*8][0]);
      }
    }
    // compute on buf: 2 k-halves x 4 row-groups
    int wrow = w*16 + lm;
    int wx = wrow & 7;
    #pragma unroll
    for(int h=0; h<2; h++){
      // W frag: segs (h*8+lq*2)^wx and (h*8+lq*2+1)^wx
      f4 lo = *(const f4*)(&Wt[buf][wrow][(( h*8 + lq*2   ) ^ wx)*4]);
      f4 hi = *(const f4*)(&Wt[buf][wrow][(( h*8 + lq*2 +1) ^ wx)*4]);
      bf16x8 bfr = pack8(lo, hi);
      #pragma unroll
      for(int rr=0; rr<4; rr++){
        int arow = rr*16 + lm;
        int as = (h*4 + lq) ^ (arow & 7);
        bf16x8 afr = *(const bf16x8*)(&At[buf][arow][as*8]);
        if(rr==0) acc0 = mfma16(afr, bfr, acc0);
        else if(rr==1) acc1 = mfma16(afr, bfr, acc1);
        else if(rr==2) acc2 = mfma16(afr, bfr, acc2);
        else acc3 = mfma16(afr, bfr, acc3);
      }
    }
    __syncthreads();
    buf ^= 1;
  }

  // epilogue: bias + store + fused row stats (16-lane butterfly per row)
  int ncol = n0 + w*16 + lm;
  float bv=0.0f, wv=0.0f; int mv=-1;
  if(ncol < V){ bv = bias[ncol]; wv = wal[ncol]; mv = mem[ncol]; }
  #pragma unroll
  for(int qi=0; qi<4; qi++){
    #pragma unroll
    for(int r=0;r<4;r++){
      float v;
      if(qi==0) v = acc0[r]+bv; else if(qi==1) v = acc1[r]+bv;
      else if(qi==2) v = acc2[r]+bv; else v = acc3[r]+bv;
      int row = lq*4 + r + 16*qi;
      if(ncol < V) outf[(size_t)row*V + ncol] = v;
      float dd = v*wv;
      float em = (mv==1) ? v : -1e30f;
      float gm = (mv==0) ? v : -1e30f;
      #pragma unroll
      for(int o=1;o<16;o<<=1){
        dd += __shfl_xor(dd,o);
        em = fmaxf(em, __shfl_xor(em,o));
        gm = fmaxf(gm, __shfl_xor(gm,o));
      }
      float pe = (mv==1) ? expf(v - em) : 0.0f;
      float pg = (mv==0) ? expf(v - gm) : 0.0f;
      #pragma unroll
      for(int o=1;o<16;o<<=1){
        pe += __shfl_xor(pe,o);
        pg += __shfl_xor(pg,o);
      }
      if(lm==0){
        sst[w][row][0]=dd; sst[w][row][1]=em; sst[w][row][2]=pe;
        sst[w][row][3]=gm; sst[w][row][4]=pg;
      }
    }
  }
  __syncthreads();
  if(tid < 64){
    float dd=0.0f, me=-1e30f, se=0.0f, mg=-1e30f, sg=0.0f;
    #pragma unroll
    for(int g=0; g<4; g++){
      dd += sst[g][tid][0];
      float m2=sst[g][tid][1], s2=sst[g][tid][2];
      float nm=fmaxf(me,m2); se = se*expf(me-nm) + s2*expf(m2-nm); me = nm;
      m2=sst[g][tid][3]; s2=sst[g][tid][4];
      nm=fmaxf(mg,m2); sg = sg*expf(mg-nm) + s2*expf(m2-nm); mg = nm;
    }
    float* pp = pstat + ((size_t)tid*NBLK + blockIdx.x)*6;
    pp[0]=dd; pp[1]=me; pp[2]=se; pp[3]=mg; pp[4]=sg;
  }
}

// ---- 9: merge per-block stats partials -> stats[b][8] ----
__global__ void k_merge(const float* __restrict__ pstat, float* __restrict__ stats){
  int b = blockIdx.x, t = threadIdx.x;
  float dd=0.0f, me=-1e30f, se=0.0f, mg=-1e30f, sg=0.0f;
  for(int i=t; i<NBLK; i+=256){
    const float* pp = pstat + ((size_t)b*NBLK + i)*6;
    dd += pp[0];
    float m2=pp[1], s2=pp[2];
    float nm=fmaxf(me,m2); se = se*expf(me-nm) + s2*expf(m2-nm); me = nm;
    m2=pp[3]; s2=pp[4];
    nm=fmaxf(mg,m2); sg = sg*expf(mg-nm) + s2*expf(m2-nm); mg = nm;
  }
  #pragma unroll
  for(int o=32;o;o>>=1){
    dd += __shfl_xor(dd,o);
    float m2=__shfl_xor(me,o), s2=__shfl_xor(se,o);
    float nm=fmaxf(me,m2); se = se*expf(me-nm) + s2*expf(m2-nm); me = nm;
    m2=__shfl_xor(mg,o); s2=__shfl_xor(sg,o);
    nm=fmaxf(mg,m2); sg = sg*expf(mg-nm) + s2*expf(m2-nm); mg = nm;
  }
  __shared__ float sm[4][5];
  int wv = t>>6;
  if((t&63)==0){ sm[wv][0]=dd; sm[wv][1]=me; sm[wv][2]=se; sm[wv][3]=mg; sm[wv][4]=sg; }
  __syncthreads();
  if(t==0){
    float D=0, M=-1e30f, S=0, M2=-1e30f, S2=0;
    for(int i=0;i<4;i++){
      D += sm[i][0];
      float m = fmaxf(M, sm[i][1]); S  = S*expf(M-m)  + sm[i][2]*expf(sm[i][1]-m);  M = m;
      float n = fmaxf(M2,sm[i][3]); S2 = S2*expf(M2-n)+ sm[i][4]*expf(sm[i][3]-n); M2 = n;
    }
    stats[b*8+0]=D; stats[b*8+1]=M; stats[b*8+2]=M2; stats[b*8+3]=S; stats[b*8+4]=S2;
  }
}

// ---- 10: dual gated softmax in-place ----
__global__ void k_final(float* __restrict__ logits, const int* __restrict__ mem,
                        const float* __restrict__ stats, const float* __restrict__ balpha){
  int v = blockIdx.x*256 + threadIdx.x;
  int b = blockIdx.y;
  if(v >= V) return;
  float dot = stats[b*8+0], me = stats[b*8+1], mg = stats[b*8+2];
  float se = stats[b*8+3],  sg = stats[b*8+4];
  float g = sigm(dot + balpha[0]);
  float l = logits[(size_t)b*V + v];
  float o = (mem[v]==1) ? (expf(l-me)/se * g) : (expf(l-mg)/sg * (1.0f-g));
  logits[(size_t)b*V + v] = o;
}

extern "C" void kernel_launch(void* const* d_in, const int* in_sizes, int n_in,
                              void* d_out, int out_size, void* d_ws, size_t ws_size,
                              hipStream_t stream){
  const int*   istep   = (const int*)d_in[0];
  const int*   iemo    = (const int*)d_in[1];
  const float* lasth   = (const float*)d_in[2];
  const float* ictx    = (const float*)d_in[3];
  const float* enc     = (const float*)d_in[4];
  const int*   emem    = (const int*)d_in[5];
  const float* emb     = (const float*)d_in[6];
  const float* eemb    = (const float*)d_in[7];
  const float* W_read  = (const float*)d_in[8];
  const float* b_read  = (const float*)d_in[9];
  const float* W_write = (const float*)d_in[10];
  const float* b_write = (const float*)d_in[11];
  const float* W_ih    = (const float*)d_in[12];
  const float* W_hh    = (const float*)d_in[13];
  const float* b_ih    = (const float*)d_in[14];
  const float* b_hh    = (const float*)d_in[15];
  const float* W_concat= (const float*)d_in[16];
  const float* b_concat= (const float*)d_in[17];
  const float* W_out   = (const float*)d_in[18];
  const float* b_out   = (const float*)d_in[19];
  const float* W_alpha = (const float*)d_in[20];
  const float* b_alpha = (const float*)d_in[21];

  short* X_b  = (short*)d_ws;                           // 64x4096 bf16
  float* emog = (float*)((char*)d_ws + 524288);         // 64x1024
  float* gp   = emog + 65536;                           // 2x64x3072 (gi partials)
  float* gh   = gp + 393216;                            // 64x3072
  float* part = gh + 196608;                            // 64x32x1024
  float* ml   = part + 2097152;                         // 64x32x2
  float* stats= ml + 4096;                              // 512
  float* pstat= stats + 512;                            // 64x786x6
  short* hid_b= (short*)(pstat + 64*NBLK*6);            // 64x1024 bf16
  short* a2_b = hid_b + 65536;                          // 64x2048 bf16
  short* cc_b = a2_b + 131072;                          // 64x1024 bf16

  float* out0 = (float*)d_out;          // [64][V]
  float* hid  = out0 + (size_t)B*V;     // [64][1024] (output: hidden)
  float* memo = hid + 65536;            // [64][1024] (output: new_M_emo)
  float* ctxo = memo + 65536;           // [64][1024] (output: context)

  k_build<<<64,256,0,stream>>>(istep, lasth, ictx, emb, X_b);
  k_pre  <<<256,256,0,stream>>>(iemo, X_b, eemb, W_read, b_read, W_hh, emog, X_b, gh);
  k_gi   <<<dim3(192,2),256,0,stream>>>(X_b, W_ih, gp);
  k_gru  <<<64,256,0,stream>>>(gp, gh, b_ih, b_hh, lasth, hid, hid_b, a2_b);
  k_flash<<<576,256,0,stream>>>(enc, hid, part, ml, hid_b, W_write, b_write, emog, memo);
  k_ctxr <<<64,256,0,stream>>>(part, ml, ctxo, a2_b);
  k_cc   <<<64,256,0,stream>>>(a2_b, W_concat, b_concat, cc_b);
  k_out  <<<NBLK,256,0,stream>>>(cc_b, W_out, b_out, W_alpha, emem, out0, pstat);
  k_merge<<<64,256,0,stream>>>(pstat, stats);
  k_final<<<dim3(197,64),256,0,stream>>>(out0, emem, stats, b_alpha);
}

// Round 13
// 181.349 us; speedup vs baseline: 1.6698x; 1.0309x over previous
//
#include <hip/hip_runtime.h>
#include <hip/hip_bf16.h>
#include <math.h>

#define B 64
#define H 1024
#define SEQ 256
#define V 50257
#define NBLK 393   // ceil(V/128)

typedef float4 f4;
typedef __attribute__((ext_vector_type(4))) float f32x4;
typedef __attribute__((ext_vector_type(8))) short bf16x8;

__device__ inline float sigm(float x){ return 1.0f/(1.0f+expf(-x)); }
__device__ inline short f2bf(float x){
  __hip_bfloat16 h = __float2bfloat16(x);
  union { __hip_bfloat16 h; short s; } u; u.h = h; return u.s;
}
__device__ inline short2 cvt2(float x, float y){
  __hip_bfloat162 h = __float22bfloat162_rn(float2{x, y});
  union { __hip_bfloat162 h; short2 s; } u; u.h = h; return u.s;
}
__device__ inline bf16x8 pack8(f4 lo, f4 hi){
  union { bf16x8 v; short2 s[4]; } u;
  u.s[0]=cvt2(lo.x,lo.y); u.s[1]=cvt2(lo.z,lo.w);
  u.s[2]=cvt2(hi.x,hi.y); u.s[3]=cvt2(hi.z,hi.w);
  return u.v;
}
__device__ inline float wrsum(float v){
  #pragma unroll
  for(int o=32;o;o>>=1) v += __shfl_xor(v,o);
  return v;
}
__device__ inline float wrmax(float v){
  #pragma unroll
  for(int o=32;o;o>>=1) v = fmaxf(v,__shfl_xor(v,o));
  return v;
}
__device__ inline f32x4 mfma16(bf16x8 a, bf16x8 b, f32x4 c){
  return __builtin_amdgcn_mfma_f32_16x16x32_bf16(a,b,c,0,0,0);
}
// async global->LDS, 16B per lane; lds dest = wave-uniform base + lane*16
__device__ inline void gll16(const void* g, void* l){
  __builtin_amdgcn_global_load_lds((const __attribute__((address_space(1))) void*)g,
                                   (__attribute__((address_space(3))) void*)l, 16, 0, 0);
}

// ---- 1: build X_b[:, :3072] = bf16[emb(iw) | lasth | ictx] ----
__global__ void k_build(const int* __restrict__ istep,
                        const float* __restrict__ lasth, const float* __restrict__ ictx,
                        const float* __restrict__ emb, short* __restrict__ X_b){
  int b = blockIdx.x; int h = threadIdx.x*4;
  int iw = istep[b];
  f4 lw = *(const f4*)(emb  + (size_t)iw*H + h);
  f4 hs = *(const f4*)(lasth + (size_t)b*H + h);
  f4 cv = *(const f4*)(ictx + (size_t)b*H + h);
  short* xb = X_b + (size_t)b*4096;
  *(short4*)(xb +        h) = make_short4(f2bf(lw.x),f2bf(lw.y),f2bf(lw.z),f2bf(lw.w));
  *(short4*)(xb + 1024 + h) = make_short4(f2bf(hs.x),f2bf(hs.y),f2bf(hs.z),f2bf(hs.w));
  *(short4*)(xb + 2048 + h) = make_short4(f2bf(cv.x),f2bf(cv.y),f2bf(cv.z),f2bf(cv.w));
}

// ---- 2: blocks 0..63: W_read gemm + sigmoid*eemb -> emog f32 + X_b[:,3072:] bf16
//         blocks 64..255: W_hh gemm (192 tiles) -> gh raw f32 ----
__launch_bounds__(256)
__global__ void k_pre(const int* __restrict__ iemo, const short* __restrict__ X_b,
                      const float* __restrict__ eemb,
                      const float* __restrict__ Wread, const float* __restrict__ bread,
                      const float* __restrict__ Whh,
                      float* __restrict__ emog, short* __restrict__ X_b_w,
                      float* __restrict__ gh){
  __shared__ float red[4][64][20];
  int tid = threadIdx.x;
  int w = tid>>6, l = tid&63, lm = l&15, lq = l>>4;
  f32x4 acc0={0,0,0,0}, acc1={0,0,0,0}, acc2={0,0,0,0}, acc3={0,0,0,0};
  int readmode = (blockIdx.x < 64);
  int tile = readmode ? blockIdx.x : (blockIdx.x - 64);
  int ncol = tile*16 + lm;
  const float* wp = readmode ? (Wread + (size_t)ncol*3072 + lq*8)
                             : (Whh   + (size_t)ncol*1024 + lq*8);
  const short* ap = readmode ? (X_b + lm*4096 + lq*8)
                             : (X_b + 1024 + lm*4096 + lq*8);
  int kbeg = readmode ? w*768 : w*256;
  int kend = readmode ? (kbeg + 768) : (kbeg + 256);
  for(int k0=kbeg; k0<kend; k0+=64){
    f4 w0 = *(const f4*)(wp + k0);
    f4 w1 = *(const f4*)(wp + k0 + 4);
    f4 w2 = *(const f4*)(wp + k0 + 32);
    f4 w3 = *(const f4*)(wp + k0 + 36);
    bf16x8 a00 = *(const bf16x8*)(ap + k0);
    bf16x8 a01 = *(const bf16x8*)(ap + k0 + 32);
    bf16x8 a10 = *(const bf16x8*)(ap + 16*4096 + k0);
    bf16x8 a11 = *(const bf16x8*)(ap + 16*4096 + k0 + 32);
    bf16x8 a20 = *(const bf16x8*)(ap + 32*4096 + k0);
    bf16x8 a21 = *(const bf16x8*)(ap + 32*4096 + k0 + 32);
    bf16x8 a30 = *(const bf16x8*)(ap + 48*4096 + k0);
    bf16x8 a31 = *(const bf16x8*)(ap + 48*4096 + k0 + 32);
    bf16x8 b0 = pack8(w0,w1), b1 = pack8(w2,w3);
    acc0 = mfma16(a00,b0,acc0); acc1 = mfma16(a10,b0,acc1);
    acc2 = mfma16(a20,b0,acc2); acc3 = mfma16(a30,b0,acc3);
    acc0 = mfma16(a01,b1,acc0); acc1 = mfma16(a11,b1,acc1);
    acc2 = mfma16(a21,b1,acc2); acc3 = mfma16(a31,b1,acc3);
  }
  #pragma unroll
  for(int r=0;r<4;r++){
    red[w][     lq*4+r][lm] = acc0[r];
    red[w][16 + lq*4+r][lm] = acc1[r];
    red[w][32 + lq*4+r][lm] = acc2[r];
    red[w][48 + lq*4+r][lm] = acc3[r];
  }
  __syncthreads();
  int m = tid>>2;
  if(readmode){
    int ie = iemo[m];
    #pragma unroll
    for(int j=0;j<4;j++){
      int c = (tid&3)*4 + j;
      float v = red[0][m][c]+red[1][m][c]+red[2][m][c]+red[3][m][c];
      int n = tile*16 + c;
      float s = sigm(v + bread[n]);
      float eg = s * eemb[(size_t)ie*1024 + n];
      emog[(size_t)m*1024 + n] = eg;
      X_b_w[(size_t)m*4096 + 3072 + n] = f2bf(eg);
    }
  } else {
    #pragma unroll
    for(int j=0;j<4;j++){
      int c = (tid&3)*4 + j;
      float v = red[0][m][c]+red[1][m][c]+red[2][m][c]+red[3][m][c];
      gh[(size_t)m*3072 + tile*16 + c] = v;
    }
  }
}

// ---- 3: gi partials = X @ W_ih^T, 2-way K-split (grid (192,2)) ----
__launch_bounds__(256)
__global__ void k_gi(const short* __restrict__ X_b, const float* __restrict__ Wih,
                     float* __restrict__ gp){
  __shared__ float red[4][64][20];
  int tid = threadIdx.x;
  int w = tid>>6, l = tid&63, lm = l&15, lq = l>>4;
  int half = blockIdx.y;
  int ncol = blockIdx.x*16 + lm;
  const float* wp = Wih + (size_t)ncol*4096 + lq*8;
  const short* ap = X_b + lm*4096 + lq*8;
  int kbeg = half*2048 + w*512, kend = kbeg + 512;
  f32x4 acc0={0,0,0,0}, acc1={0,0,0,0}, acc2={0,0,0,0}, acc3={0,0,0,0};
  for(int k0=kbeg; k0<kend; k0+=64){
    f4 w0 = *(const f4*)(wp + k0);
    f4 w1 = *(const f4*)(wp + k0 + 4);
    f4 w2 = *(const f4*)(wp + k0 + 32);
    f4 w3 = *(const f4*)(wp + k0 + 36);
    bf16x8 a00 = *(const bf16x8*)(ap + k0);
    bf16x8 a01 = *(const bf16x8*)(ap + k0 + 32);
    bf16x8 a10 = *(const bf16x8*)(ap + 16*4096 + k0);
    bf16x8 a11 = *(const bf16x8*)(ap + 16*4096 + k0 + 32);
    bf16x8 a20 = *(const bf16x8*)(ap + 32*4096 + k0);
    bf16x8 a21 = *(const bf16x8*)(ap + 32*4096 + k0 + 32);
    bf16x8 a30 = *(const bf16x8*)(ap + 48*4096 + k0);
    bf16x8 a31 = *(const bf16x8*)(ap + 48*4096 + k0 + 32);
    bf16x8 b0 = pack8(w0,w1), b1 = pack8(w2,w3);
    acc0 = mfma16(a00,b0,acc0); acc1 = mfma16(a10,b0,acc1);
    acc2 = mfma16(a20,b0,acc2); acc3 = mfma16(a30,b0,acc3);
    acc0 = mfma16(a01,b1,acc0); acc1 = mfma16(a11,b1,acc1);
    acc2 = mfma16(a21,b1,acc2); acc3 = mfma16(a31,b1,acc3);
  }
  #pragma unroll
  for(int r=0;r<4;r++){
    red[w][     lq*4+r][lm] = acc0[r];
    red[w][16 + lq*4+r][lm] = acc1[r];
    red[w][32 + lq*4+r][lm] = acc2[r];
    red[w][48 + lq*4+r][lm] = acc3[r];
  }
  __syncthreads();
  int m = tid>>2;
  #pragma unroll
  for(int j=0;j<4;j++){
    int c = (tid&3)*4 + j;
    float v = red[0][m][c]+red[1][m][c]+red[2][m][c]+red[3][m][c];
    gp[(size_t)(half*64+m)*3072 + blockIdx.x*16 + c] = v;
  }
}

// ---- 4: GRU elementwise (sums 2 gi partials + biases) ----
__global__ void k_gru(const float* __restrict__ gp, const float* __restrict__ gh,
                      const float* __restrict__ bih, const float* __restrict__ bhh,
                      const float* __restrict__ h0, float* __restrict__ hid,
                      short* __restrict__ hid_b, short* __restrict__ a2_b){
  int t = blockIdx.x*256 + threadIdx.x;   // 16384
  int b = t>>8, j = (t&255)*4;
  const float* gi0 = gp + (size_t)b*3072 + j;
  const float* gi1 = gp + (size_t)(64+b)*3072 + j;
  const float* ghb = gh + (size_t)b*3072 + j;
  f4 h0v = *(const f4*)(h0 + (size_t)b*1024 + j);
  f4 hres; short4 hb;
  #pragma unroll
  for(int c=0;c<4;c++){
    float r = sigm(gi0[c]      + gi1[c]      + bih[j+c]      + ghb[c]      + bhh[j+c]);
    float z = sigm(gi0[1024+c] + gi1[1024+c] + bih[1024+j+c] + ghb[1024+c] + bhh[1024+j+c]);
    float n = tanhf(gi0[2048+c] + gi1[2048+c] + bih[2048+j+c] + r*(ghb[2048+c] + bhh[2048+j+c]));
    float hv = ((const float*)&h0v)[c];
    float h = (1.0f - z)*n + z*hv;
    ((float*)&hres)[c] = h;
    ((short*)&hb)[c] = f2bf(h);
  }
  *(f4*)(hid + (size_t)b*1024 + j) = hres;
  *(short4*)(hid_b + (size_t)b*1024 + j) = hb;
  *(short4*)(a2_b + (size_t)b*2048 + j) = hb;
}

// ---- 5: blocks 0..511: flash attention chunks; blocks 512..575: W_write gemm ----
__launch_bounds__(256)
__global__ void k_flash(const float* __restrict__ enc, const float* __restrict__ hid,
                        float* __restrict__ part, float* __restrict__ ml,
                        const short* __restrict__ hid_b,
                        const float* __restrict__ Wwrite, const float* __restrict__ bwrite,
                        const float* __restrict__ emog, float* __restrict__ memo){
  __shared__ float red[4][64][20];
  int tid = threadIdx.x;
  int w = tid>>6, l = tid&63;
  if(blockIdx.x < 512){
    int b = blockIdx.x>>3, c = blockIdx.x&7;
    int chunk = c*4 + w;
    const float* hp = hid + (size_t)b*1024 + l*16;
    f4 q0 = *(const f4*)(hp), q1 = *(const f4*)(hp+4);
    f4 q2 = *(const f4*)(hp+8), q3 = *(const f4*)(hp+12);
    f4 cx0={0,0,0,0}, cx1={0,0,0,0}, cx2={0,0,0,0}, cx3={0,0,0,0};
    float mx = -1e30f, ls = 0.0f;
    int s0 = c*32 + w*8;
    for(int si=0; si<8; si++){
      const float* ep = enc + ((size_t)(s0+si)*64 + b)*1024 + l*16;
      f4 e0 = *(const f4*)(ep),   e1 = *(const f4*)(ep+4);
      f4 e2 = *(const f4*)(ep+8), e3 = *(const f4*)(ep+12);
      float d = e0.x*q0.x + e0.y*q0.y + e0.z*q0.z + e0.w*q0.w
              + e1.x*q1.x + e1.y*q1.y + e1.z*q1.z + e1.w*q1.w
              + e2.x*q2.x + e2.y*q2.y + e2.z*q2.z + e2.w*q2.w
              + e3.x*q3.x + e3.y*q3.y + e3.z*q3.z + e3.w*q3.w;
      d = wrsum(d);
      float mn = fmaxf(mx, d);
      float a = expf(mx - mn), p = expf(d - mn);
      ls = ls*a + p;
      cx0.x = cx0.x*a + p*e0.x; cx0.y = cx0.y*a + p*e0.y;
      cx0.z = cx0.z*a + p*e0.z; cx0.w = cx0.w*a + p*e0.w;
      cx1.x = cx1.x*a + p*e1.x; cx1.y = cx1.y*a + p*e1.y;
      cx1.z = cx1.z*a + p*e1.z; cx1.w = cx1.w*a + p*e1.w;
      cx2.x = cx2.x*a + p*e2.x; cx2.y = cx2.y*a + p*e2.y;
      cx2.z = cx2.z*a + p*e2.z; cx2.w = cx2.w*a + p*e2.w;
      cx3.x = cx3.x*a + p*e3.x; cx3.y = cx3.y*a + p*e3.y;
      cx3.z = cx3.z*a + p*e3.z; cx3.w = cx3.w*a + p*e3.w;
      mx = mn;
    }
    float* pp = part + ((size_t)b*32 + chunk)*1024 + l*16;
    *(f4*)(pp)    = cx0; *(f4*)(pp+4)  = cx1;
    *(f4*)(pp+8)  = cx2; *(f4*)(pp+12) = cx3;
    if(l==0){ ml[((size_t)b*32+chunk)*2] = mx; ml[((size_t)b*32+chunk)*2+1] = ls; }
  } else {
    int tile = blockIdx.x - 512;
    int lm = l&15, lq = l>>4;
    int ncol = tile*16 + lm;
    const float* wp = Wwrite + (size_t)ncol*1024 + lq*8;
    const short* ap = hid_b + lm*1024 + lq*8;
    int kbeg = w*256, kend = kbeg + 256;
    f32x4 acc0={0,0,0,0}, acc1={0,0,0,0}, acc2={0,0,0,0}, acc3={0,0,0,0};
    for(int k0=kbeg; k0<kend; k0+=64){
      f4 w0 = *(const f4*)(wp + k0);
      f4 w1 = *(const f4*)(wp + k0 + 4);
      f4 w2 = *(const f4*)(wp + k0 + 32);
      f4 w3 = *(const f4*)(wp + k0 + 36);
      bf16x8 a00 = *(const bf16x8*)(ap + k0);
      bf16x8 a01 = *(const bf16x8*)(ap + k0 + 32);
      bf16x8 a10 = *(const bf16x8*)(ap + 16*1024 + k0);
      bf16x8 a11 = *(const bf16x8*)(ap + 16*1024 + k0 + 32);
      bf16x8 a20 = *(const bf16x8*)(ap + 32*1024 + k0);
      bf16x8 a21 = *(const bf16x8*)(ap + 32*1024 + k0 + 32);
      bf16x8 a30 = *(const bf16x8*)(ap + 48*1024 + k0);
      bf16x8 a31 = *(const bf16x8*)(ap + 48*1024 + k0 + 32);
      bf16x8 b0 = pack8(w0,w1), b1 = pack8(w2,w3);
      acc0 = mfma16(a00,b0,acc0); acc1 = mfma16(a10,b0,acc1);
      acc2 = mfma16(a20,b0,acc2); acc3 = mfma16(a30,b0,acc3);
      acc0 = mfma16(a01,b1,acc0); acc1 = mfma16(a11,b1,acc1);
      acc2 = mfma16(a21,b1,acc2); acc3 = mfma16(a31,b1,acc3);
    }
    #pragma unroll
    for(int r=0;r<4;r++){
      red[w][     lq*4+r][lm] = acc0[r];
      red[w][16 + lq*4+r][lm] = acc1[r];
      red[w][32 + lq*4+r][lm] = acc2[r];
      red[w][48 + lq*4+r][lm] = acc3[r];
    }
    __syncthreads();
    int m = tid>>2;
    #pragma unroll
    for(int j=0;j<4;j++){
      int c = (tid&3)*4 + j;
      float v = red[0][m][c]+red[1][m][c]+red[2][m][c]+red[3][m][c];
      int n = tile*16 + c;
      memo[(size_t)m*1024 + n] = sigm(v + bwrite[n]) * emog[(size_t)m*1024 + n];
    }
  }
}

// ---- 6: merge 32 chunk partials -> context f32 (output) + a2_b[:, 1024:] bf16 ----
__global__ void k_ctxr(const float* __restrict__ part, const float* __restrict__ ml,
                       float* __restrict__ ctxo, short* __restrict__ a2_b){
  int b = blockIdx.x; int t = threadIdx.x;
  __shared__ float sscale[32];
  if(t < 64){
    float mc = (t<32) ? ml[((size_t)b*32+t)*2]   : -1e30f;
    float lc = (t<32) ? ml[((size_t)b*32+t)*2+1] : 0.0f;
    float M = wrmax(mc);
    float L = wrsum(lc * expf(mc - M));
    if(t<32) sscale[t] = expf(mc - M) / L;
  }
  __syncthreads();
  int h = t*4;
  f4 acc = {0,0,0,0};
  for(int c=0;c<32;c++){
    f4 p = *(const f4*)(part + ((size_t)b*32 + c)*1024 + h);
    float s = sscale[c];
    acc.x += s*p.x; acc.y += s*p.y; acc.z += s*p.z; acc.w += s*p.w;
  }
  *(f4*)(ctxo + (size_t)b*1024 + h) = acc;
  *(short4*)(a2_b + (size_t)b*2048 + 1024 + h) =
      make_short4(f2bf(acc.x),f2bf(acc.y),f2bf(acc.z),f2bf(acc.w));
}

// ---- 7: concat_out = tanh(a2 @ W_concat^T + b) -> cc_b bf16 ----
__launch_bounds__(256)
__global__ void k_cc(const short* __restrict__ a2_b, const float* __restrict__ Wc,
                     const float* __restrict__ bc, short* __restrict__ cc_b){
  __shared__ float red[4][64][20];
  int tid = threadIdx.x;
  int w = tid>>6, l = tid&63, lm = l&15, lq = l>>4;
  int ncol = blockIdx.x*16 + lm;
  const float* wp = Wc + (size_t)ncol*2048 + lq*8;
  const short* ap = a2_b + lm*2048 + lq*8;
  int kbeg = w*512, kend = kbeg + 512;
  f32x4 acc0={0,0,0,0}, acc1={0,0,0,0}, acc2={0,0,0,0}, acc3={0,0,0,0};
  for(int k0=kbeg; k0<kend; k0+=64){
    f4 w0 = *(const f4*)(wp + k0);
    f4 w1 = *(const f4*)(wp + k0 + 4);
    f4 w2 = *(const f4*)(wp + k0 + 32);
    f4 w3 = *(const f4*)(wp + k0 + 36);
    bf16x8 a00 = *(const bf16x8*)(ap + k0);
    bf16x8 a01 = *(const bf16x8*)(ap + k0 + 32);
    bf16x8 a10 = *(const bf16x8*)(ap + 16*2048 + k0);
    bf16x8 a11 = *(const bf16x8*)(ap + 16*2048 + k0 + 32);
    bf16x8 a20 = *(const bf16x8*)(ap + 32*2048 + k0);
    bf16x8 a21 = *(const bf16x8*)(ap + 32*2048 + k0 + 32);
    bf16x8 a30 = *(const bf16x8*)(ap + 48*2048 + k0);
    bf16x8 a31 = *(const bf16x8*)(ap + 48*2048 + k0 + 32);
    bf16x8 b0 = pack8(w0,w1), b1 = pack8(w2,w3);
    acc0 = mfma16(a00,b0,acc0); acc1 = mfma16(a10,b0,acc1);
    acc2 = mfma16(a20,b0,acc2); acc3 = mfma16(a30,b0,acc3);
    acc0 = mfma16(a01,b1,acc0); acc1 = mfma16(a11,b1,acc1);
    acc2 = mfma16(a21,b1,acc2); acc3 = mfma16(a31,b1,acc3);
  }
  #pragma unroll
  for(int r=0;r<4;r++){
    red[w][     lq*4+r][lm] = acc0[r];
    red[w][16 + lq*4+r][lm] = acc1[r];
    red[w][32 + lq*4+r][lm] = acc2[r];
    red[w][48 + lq*4+r][lm] = acc3[r];
  }
  __syncthreads();
  int m = tid>>2;
  #pragma unroll
  for(int j=0;j<4;j++){
    int c = (tid&3)*4 + j;
    float v = red[0][m][c]+red[1][m][c]+red[2][m][c]+red[3][m][c];
    int n = blockIdx.x*16 + c;
    cc_b[(size_t)m*1024 + n] = f2bf(tanhf(v + bc[n]));
  }
}

// ---- 8: logits = cc @ W_out^T + b_out. 128-col tile, gll staging (linear dest,
//         XOR-swizzled source + swizzled ds_read), dbuf K-step 64, fused stats ----
__launch_bounds__(256)
__global__ void k_out(const short* __restrict__ A, const float* __restrict__ Wm,
                      const float* __restrict__ bias, const float* __restrict__ wal,
                      const int* __restrict__ mem,
                      float* __restrict__ outf, float* __restrict__ pstat){
  __shared__ float Wt[2][128][64];   // 64 KB
  __shared__ short At[2][64][64];    // 16 KB
  float (*sst)[64][6] = (float (*)[64][6])(&At[0][0][0]);  // overlay after K-loop (12 KB)
  int tid = threadIdx.x;
  int w = tid>>6, l = tid&63;
  int lm = l&15, lq = l>>4;
  int n0 = blockIdx.x*128;

  int wRl = l>>4, wSeg = l&15;  // W: 16 lanes/row (64 f32 = 16 x 16B segs)
  int aRl = l>>3, aSeg = l&7;   // A: 8 lanes/row (64 bf16 = 8 x 16B segs)

  f32x4 accA0={0,0,0,0}, accA1={0,0,0,0}, accA2={0,0,0,0}, accA3={0,0,0,0};
  f32x4 accB0={0,0,0,0}, accB1={0,0,0,0}, accB2={0,0,0,0}, accB3={0,0,0,0};

  // ---- stage step 0 into buf 0 ----
  {
    #pragma unroll
    for(int i=0;i<8;i++){
      int R = w*32 + i*4 + wRl;
      int gr = n0 + R; if(gr > V-1) gr = V-1;
      const float* gp = Wm + (size_t)gr*1024 + (size_t)(wSeg ^ (R&7))*4;
      gll16(gp, &Wt[0][w*32 + i*4][0]);
    }
    #pragma unroll
    for(int j=0;j<2;j++){
      int R = w*16 + j*8 + aRl;
      const short* gp = A + (size_t)R*1024 + (size_t)(aSeg ^ (R&7))*8;
      gll16(gp, &At[0][w*16 + j*8][0]);
    }
  }
  __syncthreads();

  int buf = 0;
  for(int step=0; step<16; step++){
    if(step < 15){
      int k0 = (step+1)*64;
      #pragma unroll
      for(int i=0;i<8;i++){
        int R = w*32 + i*4 + wRl;
        int gr = n0 + R; if(gr > V-1) gr = V-1;
        const float* gp = Wm + (size_t)gr*1024 + k0 + (size_t)(wSeg ^ (R&7))*4;
        gll16(gp, &Wt[buf^1][w*32 + i*4][0]);
      }
      #pragma unroll
      for(int j=0;j<2;j++){
        int R = w*16 + j*8 + aRl;
        const short* gp = A + (size_t)R*1024 + k0 + (size_t)(aSeg ^ (R&7))*8;
        gll16(gp, &At[buf^1][w*16 + j*8][0]);
      }
    }
    int wrow0 = w*32 + lm, wx0 = wrow0 & 7;
    int wrow1 = w*32 + 16 + lm, wx1 = wrow1 & 7;
    #pragma unroll
    for(int h=0; h<2; h++){
      f4 lo0 = *(const f4*)(&Wt[buf][wrow0][((h*8 + lq*2  ) ^ wx0)*4]);
      f4 hi0 = *(const f4*)(&Wt[buf][wrow0][((h*8 + lq*2+1) ^ wx0)*4]);
      bf16x8 bfr0 = pack8(lo0, hi0);
      f4 lo1 = *(const f4*)(&Wt[buf][wrow1][((h*8 + lq*2  ) ^ wx1)*4]);
      f4 hi1 = *(const f4*)(&Wt[buf][wrow1][((h*8 + lq*2+1) ^ wx1)*4]);
      bf16x8 bfr1 = pack8(lo1, hi1);
      #pragma unroll
      for(int rr=0; rr<4; rr++){
        int arow = rr*16 + lm;
        int as = (h*4 + lq) ^ (arow & 7);
        bf16x8 afr = *(const bf16x8*)(&At[buf][arow][as*8]);
        if(rr==0){ accA0 = mfma16(afr,bfr0,accA0); accB0 = mfma16(afr,bfr1,accB0); }
        else if(rr==1){ accA1 = mfma16(afr,bfr0,accA1); accB1 = mfma16(afr,bfr1,accB1); }
        else if(rr==2){ accA2 = mfma16(afr,bfr0,accA2); accB2 = mfma16(afr,bfr1,accB2); }
        else { accA3 = mfma16(afr,bfr0,accA3); accB3 = mfma16(afr,bfr1,accB3); }
      }
    }
    __syncthreads();
    buf ^= 1;
  }

  // ---- epilogue: bias + store + fused row stats, cg2 = 0 then 1 ----
  for(int cg2=0; cg2<2; cg2++){
    int ncol = n0 + w*32 + cg2*16 + lm;
    float bv=0.0f, wv=0.0f; int mv=-1;
    if(ncol < V){ bv = bias[ncol]; wv = wal[ncol]; mv = mem[ncol]; }
    #pragma unroll
    for(int qi=0; qi<4; qi++){
      #pragma unroll
      for(int r=0;r<4;r++){
        float v;
        if(cg2==0){
          if(qi==0) v = accA0[r]; else if(qi==1) v = accA1[r];
          else if(qi==2) v = accA2[r]; else v = accA3[r];
        } else {
          if(qi==0) v = accB0[r]; else if(qi==1) v = accB1[r];
          else if(qi==2) v = accB2[r]; else v = accB3[r];
        }
        v += bv;
        int row = lq*4 + r + 16*qi;
        if(ncol < V) outf[(size_t)row*V + ncol] = v;
        float dd = v*wv;
        float em = (mv==1) ? v : -1e30f;
        float gm = (mv==0) ? v : -1e30f;
        #pragma unroll
        for(int o=1;o<16;o<<=1){
          dd += __shfl_xor(dd,o);
          em = fmaxf(em, __shfl_xor(em,o));
          gm = fmaxf(gm, __shfl_xor(gm,o));
        }
        float pe = (mv==1) ? expf(v - em) : 0.0f;
        float pg = (mv==0) ? expf(v - gm) : 0.0f;
        #pragma unroll
        for(int o=1;o<16;o<<=1){
          pe += __shfl_xor(pe,o);
          pg += __shfl_xor(pg,o);
        }
        if(lm==0){
          sst[w*2+cg2][row][0]=dd; sst[w*2+cg2][row][1]=em; sst[w*2+cg2][row][2]=pe;
          sst[w*2+cg2][row][3]=gm; sst[w*2+cg2][row][4]=pg;
        }
      }
    }
  }
  __syncthreads();
  if(tid < 64){
    float dd=0.0f, me=-1e30f, se=0.0f, mg=-1e30f, sg=0.0f;
    #pragma unroll
    for(int g=0; g<8; g++){
      dd += sst[g][tid][0];
      float m2=sst[g][tid][1], s2=sst[g][tid][2];
      float nm=fmaxf(me,m2); se = se*expf(me-nm) + s2*expf(m2-nm); me = nm;
      m2=sst[g][tid][3]; s2=sst[g][tid][4];
      nm=fmaxf(mg,m2); sg = sg*expf(mg-nm) + s2*expf(m2-nm); mg = nm;
    }
    float* pp = pstat + ((size_t)tid*NBLK + blockIdx.x)*6;
    pp[0]=dd; pp[1]=me; pp[2]=se; pp[3]=mg; pp[4]=sg;
  }
}

// ---- 9: merge per-block stats partials -> stats[b][8] ----
__global__ void k_merge(const float* __restrict__ pstat, float* __restrict__ stats){
  int b = blockIdx.x, t = threadIdx.x;
  float dd=0.0f, me=-1e30f, se=0.0f, mg=-1e30f, sg=0.0f;
  for(int i=t; i<NBLK; i+=256){
    const float* pp = pstat + ((size_t)b*NBLK + i)*6;
    dd += pp[0];
    float m2=pp[1], s2=pp[2];
    float nm=fmaxf(me,m2); se = se*expf(me-nm) + s2*expf(m2-nm); me = nm;
    m2=pp[3]; s2=pp[4];
    nm=fmaxf(mg,m2); sg = sg*expf(mg-nm) + s2*expf(m2-nm); mg = nm;
  }
  #pragma unroll
  for(int o=32;o;o>>=1){
    dd += __shfl_xor(dd,o);
    float m2=__shfl_xor(me,o), s2=__shfl_xor(se,o);
    float nm=fmaxf(me,m2); se = se*expf(me-nm) + s2*expf(m2-nm); me = nm;
    m2=__shfl_xor(mg,o); s2=__shfl_xor(sg,o);
    nm=fmaxf(mg,m2); sg = sg*expf(mg-nm) + s2*expf(m2-nm); mg = nm;
  }
  __shared__ float sm[4][5];
  int wv = t>>6;
  if((t&63)==0){ sm[wv][0]=dd; sm[wv][1]=me; sm[wv][2]=se; sm[wv][3]=mg; sm[wv][4]=sg; }
  __syncthreads();
  if(t==0){
    float D=0, M=-1e30f, S=0, M2=-1e30f, S2=0;
    for(int i=0;i<4;i++){
      D += sm[i][0];
      float m = fmaxf(M, sm[i][1]); S  = S*expf(M-m)  + sm[i][2]*expf(sm[i][1]-m);  M = m;
      float n = fmaxf(M2,sm[i][3]); S2 = S2*expf(M2-n)+ sm[i][4]*expf(sm[i][3]-n); M2 = n;
    }
    stats[b*8+0]=D; stats[b*8+1]=M; stats[b*8+2]=M2; stats[b*8+3]=S; stats[b*8+4]=S2;
  }
}

// ---- 10: dual gated softmax in-place ----
__global__ void k_final(float* __restrict__ logits, const int* __restrict__ mem,
                        const float* __restrict__ stats, const float* __restrict__ balpha){
  int v = blockIdx.x*256 + threadIdx.x;
  int b = blockIdx.y;
  if(v >= V) return;
  float dot = stats[b*8+0], me = stats[b*8+1], mg = stats[b*8+2];
  float se = stats[b*8+3],  sg = stats[b*8+4];
  float g = sigm(dot + balpha[0]);
  float l = logits[(size_t)b*V + v];
  float o = (mem[v]==1) ? (expf(l-me)/se * g) : (expf(l-mg)/sg * (1.0f-g));
  logits[(size_t)b*V + v] = o;
}

extern "C" void kernel_launch(void* const* d_in, const int* in_sizes, int n_in,
                              void* d_out, int out_size, void* d_ws, size_t ws_size,
                              hipStream_t stream){
  const int*   istep   = (const int*)d_in[0];
  const int*   iemo    = (const int*)d_in[1];
  const float* lasth   = (const float*)d_in[2];
  const float* ictx    = (const float*)d_in[3];
  const float* enc     = (const float*)d_in[4];
  const int*   emem    = (const int*)d_in[5];
  const float* emb     = (const float*)d_in[6];
  const float* eemb    = (const float*)d_in[7];
  const float* W_read  = (const float*)d_in[8];
  const float* b_read  = (const float*)d_in[9];
  const float* W_write = (const float*)d_in[10];
  const float* b_write = (const float*)d_in[11];
  const float* W_ih    = (const float*)d_in[12];
  const float* W_hh    = (const float*)d_in[13];
  const float* b_ih    = (const float*)d_in[14];
  const float* b_hh    = (const float*)d_in[15];
  const float* W_concat= (const float*)d_in[16];
  const float* b_concat= (const float*)d_in[17];
  const float* W_out   = (const float*)d_in[18];
  const float* b_out   = (const float*)d_in[19];
  const float* W_alpha = (const float*)d_in[20];
  const float* b_alpha = (const float*)d_in[21];

  short* X_b  = (short*)d_ws;                           // 64x4096 bf16
  float* emog = (float*)((char*)d_ws + 524288);         // 64x1024
  float* gp   = emog + 65536;                           // 2x64x3072 (gi partials)
  float* gh   = gp + 393216;                            // 64x3072
  float* part = gh + 196608;                            // 64x32x1024
  float* ml   = part + 2097152;                         // 64x32x2
  float* stats= ml + 4096;                              // 512
  float* pstat= stats + 512;                            // 64x393x6
  short* hid_b= (short*)(pstat + 64*NBLK*6);            // 64x1024 bf16
  short* a2_b = hid_b + 65536;                          // 64x2048 bf16
  short* cc_b = a2_b + 131072;                          // 64x1024 bf16

  float* out0 = (float*)d_out;          // [64][V]
  float* hid  = out0 + (size_t)B*V;     // [64][1024] (output: hidden)
  float* memo = hid + 65536;            // [64][1024] (output: new_M_emo)
  float* ctxo = memo + 65536;           // [64][1024] (output: context)

  k_build<<<64,256,0,stream>>>(istep, lasth, ictx, emb, X_b);
  k_pre  <<<256,256,0,stream>>>(iemo, X_b, eemb, W_read, b_read, W_hh, emog, X_b, gh);
  k_gi   <<<dim3(192,2),256,0,stream>>>(X_b, W_ih, gp);
  k_gru  <<<64,256,0,stream>>>(gp, gh, b_ih, b_hh, lasth, hid, hid_b, a2_b);
  k_flash<<<576,256,0,stream>>>(enc, hid, part, ml, hid_b, W_write, b_write, emog, memo);
  k_ctxr <<<64,256,0,stream>>>(part, ml, ctxo, a2_b);
  k_cc   <<<64,256,0,stream>>>(a2_b, W_concat, b_concat, cc_b);
  k_out  <<<NBLK,256,0,stream>>>(cc_b, W_out, b_out, W_alpha, emem, out0, pstat);
  k_merge<<<64,256,0,stream>>>(pstat, stats);
  k_final<<<dim3(197,64),256,0,stream>>>(out0, emem, stats, b_alpha);
}